// Round 3
// baseline (9371.635 us; speedup 1.0000x reference)
//
#include <hip/hip_runtime.h>
#include <math.h>

#define SUB 20      // sub_no
#define NC 19       // sub_no - 1
#define TSYN 200
#define THIST 50
#define BNUM 3
#define CH 512      // serial-kernel LDS chunk length (power of 2)
#define CHP (CH+4)  // padded row stride

// ---------------------------------------------------------------------------
// k_prep: assignment indices from one-hot C_syn, plus the three alpha-basis
// kernels (syn with delta shift, hist, prop).
// ---------------------------------------------------------------------------
__global__ void k_prep(const float* __restrict__ C_syn_e, const float* __restrict__ C_syn_i,
                       const float* __restrict__ W_ns_syn, const float* __restrict__ Delta_ns_syn,
                       const float* __restrict__ W_ns_hist, const float* __restrict__ W_ns_prop,
                       int* __restrict__ ae, int* __restrict__ ai,
                       float* __restrict__ ke, float* __restrict__ ki,
                       float* __restrict__ histk, float* __restrict__ propk,
                       int E, int I)
{
    int idx = blockIdx.x * blockDim.x + threadIdx.x;
    if (idx < E) {
        int a = 0;
        for (int s = 0; s < SUB; ++s) if (C_syn_e[(size_t)s * E + idx] != 0.f) a = s;
        ae[idx] = a;
        return;
    }
    idx -= E;
    if (idx < I) {
        int a = 0;
        for (int s = 0; s < SUB; ++s) if (C_syn_i[(size_t)s * I + idx] != 0.f) a = s;
        ai[idx] = a;
        return;
    }
    idx -= I;
    if (idx < SUB * 2 * TSYN) {
        int j   = idx % TSYN;
        int rem = idx / TSYN;
        int c2  = rem & 1;
        int s   = rem >> 1;
        float delta = expf(Delta_ns_syn[s * 2 + c2]);
        float ts = fmaxf((float)j - delta, 0.f);
        float acc = 0.f;
        for (int b = 0; b < BNUM; ++b) {
            float tau = expf((float)b);
            float tt = ts / tau;
            acc += W_ns_syn[s * 6 + b * 2 + c2] * tt * expf(-tt);
        }
        if (c2 == 0) ke[s * TSYN + j] = acc; else ki[s * TSYN + j] = acc;
        return;
    }
    idx -= SUB * 2 * TSYN;
    if (idx < NC * THIST) {
        int j = idx % THIST, c = idx / THIST;
        float acc = 0.f;
        for (int b = 0; b < BNUM; ++b) {
            float tau = expf((float)b);
            float tt = (float)j / tau;
            acc += W_ns_hist[c * 3 + b] * tt * expf(-tt);
        }
        histk[c * THIST + j] = acc;
        return;
    }
    idx -= NC * THIST;
    if (idx < SUB * THIST) {
        int j = idx % THIST, s = idx / THIST;
        float acc = 0.f;
        for (int b = 0; b < BNUM; ++b) {
            float tau = expf((float)b);
            float tt = (float)j / tau;
            acc += W_ns_prop[s * 3 + b] * tt * expf(-tt);
        }
        propk[s * THIST + j] = acc;
    }
}

// ---------------------------------------------------------------------------
// k_insum: segment-sum per timestep -> transposed [s][t] layouts + fused
// somatic synaptic drive syn_sT[c][t].
// ---------------------------------------------------------------------------
__global__ void k_insum(const float* __restrict__ Se, const float* __restrict__ Si,
                        const int* __restrict__ ae, const int* __restrict__ ai,
                        const float* __restrict__ W_s_syn,
                        float* __restrict__ in_eT, float* __restrict__ in_iT,
                        float* __restrict__ syn_sT,
                        int T, int E, int I)
{
    int t = blockIdx.x;
    __shared__ float le[SUB], li[SUB];
    if (threadIdx.x < SUB) { le[threadIdx.x] = 0.f; li[threadIdx.x] = 0.f; }
    __syncthreads();
    for (int e = threadIdx.x; e < E; e += blockDim.x) {
        float v = Se[(size_t)t * E + e];
        if (v != 0.f) atomicAdd(&le[ae[e]], v);
    }
    for (int i = threadIdx.x; i < I; i += blockDim.x) {
        float v = Si[(size_t)t * I + i];
        if (v != 0.f) atomicAdd(&li[ai[i]], v);
    }
    __syncthreads();
    int s = threadIdx.x;
    if (s < SUB) {
        in_eT[(size_t)s * T + t] = le[s];
        in_iT[(size_t)s * T + t] = li[s];
        if (s >= 1)
            syn_sT[(size_t)(s - 1) * T + t] =
                le[s] * W_s_syn[s * 2 + 0] + li[s] * W_s_syn[s * 2 + 1];
    }
}

// ---------------------------------------------------------------------------
// k_conv: 200-tap causal conv on transposed layouts.
// ---------------------------------------------------------------------------
__global__ void k_conv(const float* __restrict__ in_eT, const float* __restrict__ in_iT,
                       const float* __restrict__ ke, const float* __restrict__ ki,
                       float* __restrict__ syn_nsT, int T)
{
    int idx = blockIdx.x * blockDim.x + threadIdx.x;
    if (idx >= SUB * T) return;
    int s = idx / T, t = idx % T;
    float acc = 0.f;
    int jmax = min(TSYN - 1, t);
    for (int j = 0; j <= jmax; ++j)
        acc += in_eT[(size_t)s * T + t - j] * ke[s * TSYN + j]
             + in_iT[(size_t)s * T + t - j] * ki[s * TSYN + j];
    syn_nsT[idx] = acc;
}

// ---------------------------------------------------------------------------
// k_spk: serial spike recurrence, one wave. Z state lives in the low 19 bits
// of the wave ballot; per-lane sparse slot lists (jidx, w) test bits with
// per-lane shifts. P accumulated single-acc ascending j == R2 numerics.
// ---------------------------------------------------------------------------
__global__ __launch_bounds__(64) void k_spk(const float* __restrict__ syn_sT,
                      const float* __restrict__ Theta_s, const float* __restrict__ spike_decay,
                      const float* __restrict__ C_den, const float* __restrict__ W_s_prop,
                      float* __restrict__ Zout, float* __restrict__ Xout, int T)
{
    __shared__ float S[NC * CHP];
    __shared__ int smax;
    int lane = threadIdx.x;
    int c = lane;
    bool act = c < NC;

    // build per-lane sparse slot list from row mask (ascending j)
    unsigned rowmask = 0;
    if (act) {
        for (int j = 0; j < NC; ++j)
            if (C_den[(c + 1) * SUB + (j + 1)] != 0.f) rowmask |= (1u << j);
    }
    int nnz = __popc(rowmask);
    if (lane == 0) smax = 0;
    __syncthreads();
    atomicMax(&smax, nnz);
    __syncthreads();
    int kmax = __builtin_amdgcn_readfirstlane(smax);

    int   jsl[NC];
    float wsl[NC];
    {
        unsigned m = rowmask;
        #pragma unroll
        for (int k = 0; k < NC; ++k) {
            int j = (m != 0u) ? (__ffs(m) - 1) : 0;
            jsl[k] = j;
            wsl[k] = (m != 0u) ? W_s_prop[j] : 0.f;
            m &= (m - 1);
        }
    }
    float theta = act ? Theta_s[c] : 0.f;
    float decay = act ? spike_decay[c] : 0.f;

    float x = 0.f;
    unsigned zlo = 0u;   // ballot low 32 bits; bits 0..18 are the Z state
    for (int t0 = 0; t0 < T; t0 += CH) {
        int len = min(CH, T - t0);
        __syncthreads();
        for (int r = lane; r < (NC * CH) / 4; r += 64) {
            int e = r * 4;
            int cc = e >> 9;
            int tl = e & (CH - 1);
            if (tl < len) {
                float4 v = *(const float4*)(syn_sT + (size_t)cc * T + t0 + tl);
                *(float4*)(&S[cc * CHP + tl]) = v;
            }
        }
        __syncthreads();
        float4 cur = act ? *(float4*)(&S[c * CHP]) : make_float4(0.f, 0.f, 0.f, 0.f);
        for (int g = 0; g < len; g += 4) {
            float4 nxt = (act && g + 4 < len) ? *(float4*)(&S[c * CHP + g + 4]) : cur;
            #pragma unroll
            for (int q = 0; q < 4; ++q) {
                float syn = (q == 0) ? cur.x : (q == 1) ? cur.y : (q == 2) ? cur.z : cur.w;
                float P = 0.f;
                #pragma unroll
                for (int k = 0; k < NC; ++k) {
                    if (k < kmax) {
                        float b = (float)((zlo >> jsl[k]) & 1u);
                        P = fmaf(b, wsl[k], P);   // exact: skipped zeros are no-ops
                    }
                }
                float xin = fmaf(x, decay, syn);
                xin += P;
                xin += theta;
                int t = t0 + g + q;
                if (t < T) {
                    bool zb = xin >= 0.f;
                    zlo = (unsigned)__ballot(zb);   // bits >=19 garbage, never read
                    x = zb ? 0.f : xin;
                    if (act) {
                        Zout[(size_t)t * NC + c] = zb ? 1.f : 0.f;
                        Xout[(size_t)t * NC + c] = x;
                    }
                }
            }
            cur = nxt;
        }
    }
}

// ---------------------------------------------------------------------------
// k_pz: PZ_T[s][u] = sum_c Z[u,c] * C_den[s, c+1]
// ---------------------------------------------------------------------------
__global__ void k_pz(const float* __restrict__ Z, const float* __restrict__ C_den,
                     float* __restrict__ PZ_T, int T)
{
    int idx = blockIdx.x * blockDim.x + threadIdx.x;
    if (idx >= SUB * T) return;
    int s = idx / T, u = idx % T;
    float acc = 0.f;
    #pragma unroll
    for (int c = 0; c < NC; ++c)
        acc += Z[(size_t)u * NC + c] * C_den[s * SUB + c + 1];
    PZ_T[idx] = acc;
}

// ---------------------------------------------------------------------------
// k_A: A_T[s][t] = syn_ns + Theta_ns + f_prop (+ f_hist for s>=1)
// ---------------------------------------------------------------------------
__global__ void k_A(const float* __restrict__ syn_nsT, const float* __restrict__ PZ_T,
                    const float* __restrict__ Z, const float* __restrict__ histk,
                    const float* __restrict__ propk, const float* __restrict__ Theta_ns,
                    float* __restrict__ A_T, int T)
{
    int idx = blockIdx.x * blockDim.x + threadIdx.x;
    if (idx >= SUB * T) return;
    int s = idx / T, t = idx % T;
    float acc = syn_nsT[idx] + Theta_ns[s];
    int jmax = min(THIST - 1, t - 1);
    for (int j = 0; j <= jmax; ++j)
        acc += propk[s * THIST + j] * PZ_T[(size_t)s * T + t - 1 - j];
    if (s > 0) {
        int c = s - 1;
        for (int j = 0; j <= jmax; ++j)
            acc += histk[c * THIST + j] * Z[(size_t)(t - 1 - j) * NC + c];
    }
    A_T[idx] = acc;
}

// ---------------------------------------------------------------------------
// k_y: serial Y recurrence, one wave. Cross-lane gather of y via ds_bpermute
// over sparse per-lane slot lists (one LDS-unit latency per step, batched).
// ---------------------------------------------------------------------------
__global__ __launch_bounds__(64) void k_y(const float* __restrict__ A_T,
                    const float* __restrict__ C_den, const float* __restrict__ W_ns_sub,
                    const float* __restrict__ V_o,
                    float* __restrict__ Vout, float* __restrict__ Yout, int T)
{
    __shared__ float S[SUB * CHP];
    __shared__ int smax;
    int lane = threadIdx.x;
    int s = lane;
    bool act = s < SUB;

    unsigned rowmask = 0;
    if (act) {
        for (int j = 0; j < SUB; ++j)
            if (C_den[s * SUB + j] != 0.f) rowmask |= (1u << j);
    }
    int nnz = __popc(rowmask);
    if (lane == 0) smax = 0;
    __syncthreads();
    atomicMax(&smax, nnz);
    __syncthreads();
    int kmax = __builtin_amdgcn_readfirstlane(smax);

    int   asl[SUB];
    float wsl[SUB];
    {
        unsigned m = rowmask;
        #pragma unroll
        for (int k = 0; k < SUB; ++k) {
            int j = (m != 0u) ? (__ffs(m) - 1) : lane;  // pad: gather own lane
            asl[k] = 4 * j;
            wsl[k] = (m != 0u) ? C_den[s * SUB + j] : 0.f;
            m &= (m - 1);
        }
    }
    float wsub = act ? W_ns_sub[s] : 0.f;
    float vo = V_o[0];

    float y = 0.f;
    for (int t0 = 0; t0 < T; t0 += CH) {
        int len = min(CH, T - t0);
        __syncthreads();
        for (int r = lane; r < (SUB * CH) / 4; r += 64) {
            int e = r * 4;
            int cc = e >> 9;
            int tl = e & (CH - 1);
            if (tl < len) {
                float4 v = *(const float4*)(A_T + (size_t)cc * T + t0 + tl);
                *(float4*)(&S[cc * CHP + tl]) = v;
            }
        }
        __syncthreads();
        float4 cur = act ? *(float4*)(&S[s * CHP]) : make_float4(0.f, 0.f, 0.f, 0.f);
        for (int g = 0; g < len; g += 4) {
            float4 nxt = (act && g + 4 < len) ? *(float4*)(&S[s * CHP + g + 4]) : cur;
            #pragma unroll
            for (int q = 0; q < 4; ++q) {
                float a = (q == 0) ? cur.x : (q == 1) ? cur.y : (q == 2) ? cur.z : cur.w;
                // batched register gather of y from producer lanes
                float gth[SUB];
                #pragma unroll
                for (int k = 0; k < SUB; ++k)
                    if (k < kmax)
                        gth[k] = __int_as_float(
                            __builtin_amdgcn_ds_bpermute(asl[k], __float_as_int(y)));
                float u0 = a, u1 = 0.f, u2 = 0.f, u3 = 0.f;
                #pragma unroll
                for (int k = 0; k < SUB; ++k) {
                    if (k < kmax) {
                        float p = gth[k] * wsl[k];
                        if ((k & 3) == 0) u0 += p;
                        else if ((k & 3) == 1) u1 += p;
                        else if ((k & 3) == 2) u2 += p;
                        else u3 += p;
                    }
                }
                float u = (u0 + u1) + (u2 + u3);
                int t = t0 + g + q;
                if (t < T) {
                    y = wsub / (1.f + __expf(-u));
                    if (act) {
                        float* p = (s == 0) ? (Vout + t) : (Yout + (size_t)t * NC + (s - 1));
                        *p = (s == 0) ? y + vo : y;
                    }
                }
            }
            cur = nxt;
        }
    }
}

// ---------------------------------------------------------------------------
extern "C" void kernel_launch(void* const* d_in, const int* in_sizes, int n_in,
                              void* d_out, int out_size, void* d_ws, size_t ws_size,
                              hipStream_t stream)
{
    const float* S_e          = (const float*)d_in[0];
    const float* S_i          = (const float*)d_in[1];
    const float* C_den        = (const float*)d_in[2];
    const float* C_syn_e      = (const float*)d_in[3];
    const float* C_syn_i      = (const float*)d_in[4];
    const float* W_s_syn      = (const float*)d_in[5];
    const float* W_ns_syn     = (const float*)d_in[6];
    const float* Delta_ns_syn = (const float*)d_in[7];
    const float* W_ns_sub     = (const float*)d_in[8];
    const float* V_o          = (const float*)d_in[9];
    const float* Theta_s      = (const float*)d_in[10];
    const float* Theta_ns     = (const float*)d_in[11];
    const float* W_ns_hist    = (const float*)d_in[12];
    const float* W_s_prop     = (const float*)d_in[13];
    const float* W_ns_prop    = (const float*)d_in[14];
    const float* spike_decay  = (const float*)d_in[15];

    int E = in_sizes[3] / SUB;
    int I = in_sizes[4] / SUB;
    int T = in_sizes[0] / E;

    float* out  = (float*)d_out;
    float* Vout = out;                           // [T]
    float* Yout = out + (size_t)T;               // [T, 19]
    float* Zout = out + (size_t)T * (1 + NC);    // [T, 19]
    float* Xout = out + (size_t)T * (1 + 2*NC);  // [T, 19]

    float* w       = (float*)d_ws;
    float* in_eT   = w;  w += (size_t)SUB * T;   // aliased as A_T after k_conv
    float* in_iT   = w;  w += (size_t)SUB * T;
    float* syn_sT  = w;  w += (size_t)NC * T;
    float* syn_nsT = w;  w += (size_t)SUB * T;
    float* PZ_T    = w;  w += (size_t)SUB * T;
    float* ke      = w;  w += SUB * TSYN;
    float* ki      = w;  w += SUB * TSYN;
    float* histk   = w;  w += NC * THIST;
    float* propk   = w;  w += SUB * THIST;
    int*   ae      = (int*)w;
    int*   ai      = ae + E;
    float* A_T     = in_eT;   // in_eT dead after k_conv

    int nprep = E + I + SUB * 2 * TSYN + NC * THIST + SUB * THIST;
    hipLaunchKernelGGL(k_prep, dim3((nprep + 255) / 256), dim3(256), 0, stream,
                       C_syn_e, C_syn_i, W_ns_syn, Delta_ns_syn, W_ns_hist, W_ns_prop,
                       ae, ai, ke, ki, histk, propk, E, I);
    hipLaunchKernelGGL(k_insum, dim3(T), dim3(256), 0, stream,
                       S_e, S_i, ae, ai, W_s_syn, in_eT, in_iT, syn_sT, T, E, I);
    hipLaunchKernelGGL(k_conv, dim3((SUB * T + 255) / 256), dim3(256), 0, stream,
                       in_eT, in_iT, ke, ki, syn_nsT, T);
    hipLaunchKernelGGL(k_spk, dim3(1), dim3(64), 0, stream,
                       syn_sT, Theta_s, spike_decay, C_den, W_s_prop, Zout, Xout, T);
    hipLaunchKernelGGL(k_pz, dim3((SUB * T + 255) / 256), dim3(256), 0, stream,
                       Zout, C_den, PZ_T, T);
    hipLaunchKernelGGL(k_A, dim3((SUB * T + 255) / 256), dim3(256), 0, stream,
                       syn_nsT, PZ_T, Zout, histk, propk, Theta_ns, A_T, T);
    hipLaunchKernelGGL(k_y, dim3(1), dim3(64), 0, stream,
                       A_T, C_den, W_ns_sub, V_o, Vout, Yout, T);
}

// Round 4
// 5227.791 us; speedup vs baseline: 1.7927x; 1.7927x over previous
//
#include <hip/hip_runtime.h>
#include <math.h>

#define SUB 20      // sub_no
#define NC 19       // sub_no - 1
#define TSYN 200
#define THIST 50
#define BNUM 3
#define CH 512      // serial-kernel LDS chunk length (power of 2)
#define CHP (CH+4)  // padded row stride

// ---------------------------------------------------------------------------
// k_prep: assignment indices from one-hot C_syn, plus the three alpha-basis
// kernels (syn with delta shift, hist, prop).
// ---------------------------------------------------------------------------
__global__ void k_prep(const float* __restrict__ C_syn_e, const float* __restrict__ C_syn_i,
                       const float* __restrict__ W_ns_syn, const float* __restrict__ Delta_ns_syn,
                       const float* __restrict__ W_ns_hist, const float* __restrict__ W_ns_prop,
                       int* __restrict__ ae, int* __restrict__ ai,
                       float* __restrict__ ke, float* __restrict__ ki,
                       float* __restrict__ histk, float* __restrict__ propk,
                       int E, int I)
{
    int idx = blockIdx.x * blockDim.x + threadIdx.x;
    if (idx < E) {
        int a = 0;
        for (int s = 0; s < SUB; ++s) if (C_syn_e[(size_t)s * E + idx] != 0.f) a = s;
        ae[idx] = a;
        return;
    }
    idx -= E;
    if (idx < I) {
        int a = 0;
        for (int s = 0; s < SUB; ++s) if (C_syn_i[(size_t)s * I + idx] != 0.f) a = s;
        ai[idx] = a;
        return;
    }
    idx -= I;
    if (idx < SUB * 2 * TSYN) {
        int j   = idx % TSYN;
        int rem = idx / TSYN;
        int c2  = rem & 1;
        int s   = rem >> 1;
        float delta = expf(Delta_ns_syn[s * 2 + c2]);
        float ts = fmaxf((float)j - delta, 0.f);
        float acc = 0.f;
        for (int b = 0; b < BNUM; ++b) {
            float tau = expf((float)b);
            float tt = ts / tau;
            acc += W_ns_syn[s * 6 + b * 2 + c2] * tt * expf(-tt);
        }
        if (c2 == 0) ke[s * TSYN + j] = acc; else ki[s * TSYN + j] = acc;
        return;
    }
    idx -= SUB * 2 * TSYN;
    if (idx < NC * THIST) {
        int j = idx % THIST, c = idx / THIST;
        float acc = 0.f;
        for (int b = 0; b < BNUM; ++b) {
            float tau = expf((float)b);
            float tt = (float)j / tau;
            acc += W_ns_hist[c * 3 + b] * tt * expf(-tt);
        }
        histk[c * THIST + j] = acc;
        return;
    }
    idx -= NC * THIST;
    if (idx < SUB * THIST) {
        int j = idx % THIST, s = idx / THIST;
        float acc = 0.f;
        for (int b = 0; b < BNUM; ++b) {
            float tau = expf((float)b);
            float tt = (float)j / tau;
            acc += W_ns_prop[s * 3 + b] * tt * expf(-tt);
        }
        propk[s * THIST + j] = acc;
    }
}

// ---------------------------------------------------------------------------
// k_insum: segment-sum per timestep -> transposed [s][t] layouts + fused
// somatic synaptic drive syn_sT[c][t].
// ---------------------------------------------------------------------------
__global__ void k_insum(const float* __restrict__ Se, const float* __restrict__ Si,
                        const int* __restrict__ ae, const int* __restrict__ ai,
                        const float* __restrict__ W_s_syn,
                        float* __restrict__ in_eT, float* __restrict__ in_iT,
                        float* __restrict__ syn_sT,
                        int T, int E, int I)
{
    int t = blockIdx.x;
    __shared__ float le[SUB], li[SUB];
    if (threadIdx.x < SUB) { le[threadIdx.x] = 0.f; li[threadIdx.x] = 0.f; }
    __syncthreads();
    for (int e = threadIdx.x; e < E; e += blockDim.x) {
        float v = Se[(size_t)t * E + e];
        if (v != 0.f) atomicAdd(&le[ae[e]], v);
    }
    for (int i = threadIdx.x; i < I; i += blockDim.x) {
        float v = Si[(size_t)t * I + i];
        if (v != 0.f) atomicAdd(&li[ai[i]], v);
    }
    __syncthreads();
    int s = threadIdx.x;
    if (s < SUB) {
        in_eT[(size_t)s * T + t] = le[s];
        in_iT[(size_t)s * T + t] = li[s];
        if (s >= 1)
            syn_sT[(size_t)(s - 1) * T + t] =
                le[s] * W_s_syn[s * 2 + 0] + li[s] * W_s_syn[s * 2 + 1];
    }
}

// ---------------------------------------------------------------------------
// k_conv: 200-tap causal conv on transposed layouts.
// ---------------------------------------------------------------------------
__global__ void k_conv(const float* __restrict__ in_eT, const float* __restrict__ in_iT,
                       const float* __restrict__ ke, const float* __restrict__ ki,
                       float* __restrict__ syn_nsT, int T)
{
    int idx = blockIdx.x * blockDim.x + threadIdx.x;
    if (idx >= SUB * T) return;
    int s = idx / T, t = idx % T;
    float acc = 0.f;
    int jmax = min(TSYN - 1, t);
    for (int j = 0; j <= jmax; ++j)
        acc += in_eT[(size_t)s * T + t - j] * ke[s * TSYN + j]
             + in_iT[(size_t)s * T + t - j] * ki[s * TSYN + j];
    syn_nsT[idx] = acc;
}

// ---------------------------------------------------------------------------
// k_spk: serial spike recurrence, one wave. Z state = low 19 bits of the
// wave ballot (wave-uniform SGPR) -> coupling dot needs NO cross-lane reads:
// per compile-time j: 1 SALU bit-test + v_cvt + fmac. b in {0,1} exact, so P
// is bit-identical to R2's readlane chain (ascending j, single accumulator).
// ---------------------------------------------------------------------------
__global__ __launch_bounds__(64) void k_spk(const float* __restrict__ syn_sT,
                      const float* __restrict__ Theta_s, const float* __restrict__ spike_decay,
                      const float* __restrict__ C_den, const float* __restrict__ W_s_prop,
                      float* __restrict__ Zout, float* __restrict__ Xout, int T)
{
    __shared__ float S[NC * CHP];
    int lane = threadIdx.x;
    int c = lane;
    bool act = c < NC;
    float M[NC];
    #pragma unroll
    for (int j = 0; j < NC; ++j)
        M[j] = act ? C_den[(c + 1) * SUB + (j + 1)] * W_s_prop[j] : 0.f;
    float theta = act ? Theta_s[c] : 0.f;
    float decay = act ? spike_decay[c] : 0.f;

    float x = 0.f;
    unsigned zlo = 0u;   // ballot low 32 bits; bits 0..18 = Z state, rest never read
    for (int t0 = 0; t0 < T; t0 += CH) {
        int len = min(CH, T - t0);
        __syncthreads();
        for (int r = lane; r < (NC * CH) / 4; r += 64) {
            int e = r * 4;
            int cc = e >> 9;          // e / CH
            int tl = e & (CH - 1);    // e % CH
            if (tl < len) {
                float4 v = *(const float4*)(syn_sT + (size_t)cc * T + t0 + tl);
                *(float4*)(&S[cc * CHP + tl]) = v;
            }
        }
        __syncthreads();
        float4 cur = act ? *(float4*)(&S[c * CHP]) : make_float4(0.f, 0.f, 0.f, 0.f);
        for (int g = 0; g < len; g += 4) {
            float4 nxt = (act && g + 4 < len) ? *(float4*)(&S[c * CHP + g + 4]) : cur;
            #pragma unroll
            for (int q = 0; q < 4; ++q) {
                float syn = (q == 0) ? cur.x : (q == 1) ? cur.y : (q == 2) ? cur.z : cur.w;
                float P = 0.f;
                #pragma unroll
                for (int j = 0; j < NC; ++j) {          // branchless, compile-time shifts
                    float b = (float)((zlo >> j) & 1u); // SALU bfe + v_cvt (sgpr src)
                    P = fmaf(b, M[j], P);               // exact: b in {0,1}
                }
                float xin = fmaf(x, decay, syn);
                xin += P;
                xin += theta;
                int t = t0 + g + q;
                if (t < T) {
                    bool zb = xin >= 0.f;
                    zlo = (unsigned)__ballot(zb);
                    x = zb ? 0.f : xin;
                    if (act) {
                        Zout[(size_t)t * NC + c] = zb ? 1.f : 0.f;
                        Xout[(size_t)t * NC + c] = x;
                    }
                }
            }
            cur = nxt;
        }
    }
}

// ---------------------------------------------------------------------------
// k_pz: PZ_T[s][u] = sum_c Z[u,c] * C_den[s, c+1]
// ---------------------------------------------------------------------------
__global__ void k_pz(const float* __restrict__ Z, const float* __restrict__ C_den,
                     float* __restrict__ PZ_T, int T)
{
    int idx = blockIdx.x * blockDim.x + threadIdx.x;
    if (idx >= SUB * T) return;
    int s = idx / T, u = idx % T;
    float acc = 0.f;
    #pragma unroll
    for (int c = 0; c < NC; ++c)
        acc += Z[(size_t)u * NC + c] * C_den[s * SUB + c + 1];
    PZ_T[idx] = acc;
}

// ---------------------------------------------------------------------------
// k_A: A_T[s][t] = syn_ns + Theta_ns + f_prop (+ f_hist for s>=1)
// ---------------------------------------------------------------------------
__global__ void k_A(const float* __restrict__ syn_nsT, const float* __restrict__ PZ_T,
                    const float* __restrict__ Z, const float* __restrict__ histk,
                    const float* __restrict__ propk, const float* __restrict__ Theta_ns,
                    float* __restrict__ A_T, int T)
{
    int idx = blockIdx.x * blockDim.x + threadIdx.x;
    if (idx >= SUB * T) return;
    int s = idx / T, t = idx % T;
    float acc = syn_nsT[idx] + Theta_ns[s];
    int jmax = min(THIST - 1, t - 1);
    for (int j = 0; j <= jmax; ++j)
        acc += propk[s * THIST + j] * PZ_T[(size_t)s * T + t - 1 - j];
    if (s > 0) {
        int c = s - 1;
        for (int j = 0; j <= jmax; ++j)
            acc += histk[c * THIST + j] * Z[(size_t)(t - 1 - j) * NC + c];
    }
    A_T[idx] = acc;
}

// ---------------------------------------------------------------------------
// k_y: serial Y recurrence, one wave. Cross-lane exchange = ONE LDS round
// trip per step: unconditional ds_write of y, then 5 broadcast ds_read_b128
// of the whole 20-vector (same address all lanes -> conflict-free). Single
// wave => HW DS ordering guarantees write-before-read; wave_barrier pins
// compiler ordering. Accumulation replicates R2's 4-acc stride-4 grouping.
// ---------------------------------------------------------------------------
__global__ __launch_bounds__(64) void k_y(const float* __restrict__ A_T,
                    const float* __restrict__ C_den, const float* __restrict__ W_ns_sub,
                    const float* __restrict__ V_o,
                    float* __restrict__ Vout, float* __restrict__ Yout, int T)
{
    __shared__ float S[SUB * CHP];
    __shared__ __align__(16) float ybc[64];
    int lane = threadIdx.x;
    int s = lane;
    bool act = s < SUB;
    float Crow[SUB];
    #pragma unroll
    for (int j = 0; j < SUB; ++j)
        Crow[j] = act ? C_den[s * SUB + j] : 0.f;
    float wsub = act ? W_ns_sub[s] : 0.f;
    float vo = V_o[0];

    ybc[lane] = 0.f;
    __syncthreads();

    for (int t0 = 0; t0 < T; t0 += CH) {
        int len = min(CH, T - t0);
        __syncthreads();
        for (int r = lane; r < (SUB * CH) / 4; r += 64) {
            int e = r * 4;
            int cc = e >> 9;
            int tl = e & (CH - 1);
            if (tl < len) {
                float4 v = *(const float4*)(A_T + (size_t)cc * T + t0 + tl);
                *(float4*)(&S[cc * CHP + tl]) = v;
            }
        }
        __syncthreads();
        float4 cur = act ? *(float4*)(&S[s * CHP]) : make_float4(0.f, 0.f, 0.f, 0.f);
        for (int g = 0; g < len; g += 4) {
            float4 nxt = (act && g + 4 < len) ? *(float4*)(&S[s * CHP + g + 4]) : cur;
            #pragma unroll
            for (int q = 0; q < 4; ++q) {
                float a = (q == 0) ? cur.x : (q == 1) ? cur.y : (q == 2) ? cur.z : cur.w;
                // broadcast read of y(t-1) vector (5x ds_read_b128, one wait)
                __builtin_amdgcn_wave_barrier();
                float4 Y0 = *(const float4*)(&ybc[0]);
                float4 Y1 = *(const float4*)(&ybc[4]);
                float4 Y2 = *(const float4*)(&ybc[8]);
                float4 Y3 = *(const float4*)(&ybc[12]);
                float4 Y4 = *(const float4*)(&ybc[16]);
                float u0 = a, u1 = 0.f, u2 = 0.f, u3 = 0.f;
                u0 += Crow[0]  * Y0.x;  u1 += Crow[1]  * Y0.y;
                u2 += Crow[2]  * Y0.z;  u3 += Crow[3]  * Y0.w;
                u0 += Crow[4]  * Y1.x;  u1 += Crow[5]  * Y1.y;
                u2 += Crow[6]  * Y1.z;  u3 += Crow[7]  * Y1.w;
                u0 += Crow[8]  * Y2.x;  u1 += Crow[9]  * Y2.y;
                u2 += Crow[10] * Y2.z;  u3 += Crow[11] * Y2.w;
                u0 += Crow[12] * Y3.x;  u1 += Crow[13] * Y3.y;
                u2 += Crow[14] * Y3.z;  u3 += Crow[15] * Y3.w;
                u0 += Crow[16] * Y4.x;  u1 += Crow[17] * Y4.y;
                u2 += Crow[18] * Y4.z;  u3 += Crow[19] * Y4.w;
                float u = (u0 + u1) + (u2 + u3);
                int t = t0 + g + q;
                if (t < T) {
                    float y = wsub / (1.f + __expf(-u));   // lanes>=20: 0/(...) = 0
                    __builtin_amdgcn_wave_barrier();
                    ybc[lane] = y;
                    if (act) {
                        float* p = (s == 0) ? (Vout + t) : (Yout + (size_t)t * NC + (s - 1));
                        *p = (s == 0) ? y + vo : y;
                    }
                }
            }
            cur = nxt;
        }
    }
}

// ---------------------------------------------------------------------------
extern "C" void kernel_launch(void* const* d_in, const int* in_sizes, int n_in,
                              void* d_out, int out_size, void* d_ws, size_t ws_size,
                              hipStream_t stream)
{
    const float* S_e          = (const float*)d_in[0];
    const float* S_i          = (const float*)d_in[1];
    const float* C_den        = (const float*)d_in[2];
    const float* C_syn_e      = (const float*)d_in[3];
    const float* C_syn_i      = (const float*)d_in[4];
    const float* W_s_syn      = (const float*)d_in[5];
    const float* W_ns_syn     = (const float*)d_in[6];
    const float* Delta_ns_syn = (const float*)d_in[7];
    const float* W_ns_sub     = (const float*)d_in[8];
    const float* V_o          = (const float*)d_in[9];
    const float* Theta_s      = (const float*)d_in[10];
    const float* Theta_ns     = (const float*)d_in[11];
    const float* W_ns_hist    = (const float*)d_in[12];
    const float* W_s_prop     = (const float*)d_in[13];
    const float* W_ns_prop    = (const float*)d_in[14];
    const float* spike_decay  = (const float*)d_in[15];

    int E = in_sizes[3] / SUB;
    int I = in_sizes[4] / SUB;
    int T = in_sizes[0] / E;

    float* out  = (float*)d_out;
    float* Vout = out;                           // [T]
    float* Yout = out + (size_t)T;               // [T, 19]
    float* Zout = out + (size_t)T * (1 + NC);    // [T, 19]
    float* Xout = out + (size_t)T * (1 + 2*NC);  // [T, 19]

    float* w       = (float*)d_ws;
    float* in_eT   = w;  w += (size_t)SUB * T;   // aliased as A_T after k_conv
    float* in_iT   = w;  w += (size_t)SUB * T;
    float* syn_sT  = w;  w += (size_t)NC * T;
    float* syn_nsT = w;  w += (size_t)SUB * T;
    float* PZ_T    = w;  w += (size_t)SUB * T;
    float* ke      = w;  w += SUB * TSYN;
    float* ki      = w;  w += SUB * TSYN;
    float* histk   = w;  w += NC * THIST;
    float* propk   = w;  w += SUB * THIST;
    int*   ae      = (int*)w;
    int*   ai      = ae + E;
    float* A_T     = in_eT;   // in_eT dead after k_conv

    int nprep = E + I + SUB * 2 * TSYN + NC * THIST + SUB * THIST;
    hipLaunchKernelGGL(k_prep, dim3((nprep + 255) / 256), dim3(256), 0, stream,
                       C_syn_e, C_syn_i, W_ns_syn, Delta_ns_syn, W_ns_hist, W_ns_prop,
                       ae, ai, ke, ki, histk, propk, E, I);
    hipLaunchKernelGGL(k_insum, dim3(T), dim3(256), 0, stream,
                       S_e, S_i, ae, ai, W_s_syn, in_eT, in_iT, syn_sT, T, E, I);
    hipLaunchKernelGGL(k_conv, dim3((SUB * T + 255) / 256), dim3(256), 0, stream,
                       in_eT, in_iT, ke, ki, syn_nsT, T);
    hipLaunchKernelGGL(k_spk, dim3(1), dim3(64), 0, stream,
                       syn_sT, Theta_s, spike_decay, C_den, W_s_prop, Zout, Xout, T);
    hipLaunchKernelGGL(k_pz, dim3((SUB * T + 255) / 256), dim3(256), 0, stream,
                       Zout, C_den, PZ_T, T);
    hipLaunchKernelGGL(k_A, dim3((SUB * T + 255) / 256), dim3(256), 0, stream,
                       syn_nsT, PZ_T, Zout, histk, propk, Theta_ns, A_T, T);
    hipLaunchKernelGGL(k_y, dim3(1), dim3(64), 0, stream,
                       A_T, C_den, W_ns_sub, V_o, Vout, Yout, T);
}

// Round 5
// 4252.752 us; speedup vs baseline: 2.2037x; 1.2293x over previous
//
#include <hip/hip_runtime.h>
#include <math.h>

#define SUB 20      // sub_no
#define NC 19       // sub_no - 1
#define TSYN 200
#define THIST 50
#define BNUM 3
#define CHS 256     // serial-kernel LDS chunk length (power of 2)
#define CHSP (CHS+4) // padded row stride (16B-aligned rows: 260*4B = 65*16)

// ---------------------------------------------------------------------------
// k_prep: assignment indices from one-hot C_syn, plus the three alpha-basis
// kernels (syn with delta shift, hist, prop).
// ---------------------------------------------------------------------------
__global__ void k_prep(const float* __restrict__ C_syn_e, const float* __restrict__ C_syn_i,
                       const float* __restrict__ W_ns_syn, const float* __restrict__ Delta_ns_syn,
                       const float* __restrict__ W_ns_hist, const float* __restrict__ W_ns_prop,
                       int* __restrict__ ae, int* __restrict__ ai,
                       float* __restrict__ ke, float* __restrict__ ki,
                       float* __restrict__ histk, float* __restrict__ propk,
                       int E, int I)
{
    int idx = blockIdx.x * blockDim.x + threadIdx.x;
    if (idx < E) {
        int a = 0;
        for (int s = 0; s < SUB; ++s) if (C_syn_e[(size_t)s * E + idx] != 0.f) a = s;
        ae[idx] = a;
        return;
    }
    idx -= E;
    if (idx < I) {
        int a = 0;
        for (int s = 0; s < SUB; ++s) if (C_syn_i[(size_t)s * I + idx] != 0.f) a = s;
        ai[idx] = a;
        return;
    }
    idx -= I;
    if (idx < SUB * 2 * TSYN) {
        int j   = idx % TSYN;
        int rem = idx / TSYN;
        int c2  = rem & 1;
        int s   = rem >> 1;
        float delta = expf(Delta_ns_syn[s * 2 + c2]);
        float ts = fmaxf((float)j - delta, 0.f);
        float acc = 0.f;
        for (int b = 0; b < BNUM; ++b) {
            float tau = expf((float)b);
            float tt = ts / tau;
            acc += W_ns_syn[s * 6 + b * 2 + c2] * tt * expf(-tt);
        }
        if (c2 == 0) ke[s * TSYN + j] = acc; else ki[s * TSYN + j] = acc;
        return;
    }
    idx -= SUB * 2 * TSYN;
    if (idx < NC * THIST) {
        int j = idx % THIST, c = idx / THIST;
        float acc = 0.f;
        for (int b = 0; b < BNUM; ++b) {
            float tau = expf((float)b);
            float tt = (float)j / tau;
            acc += W_ns_hist[c * 3 + b] * tt * expf(-tt);
        }
        histk[c * THIST + j] = acc;
        return;
    }
    idx -= NC * THIST;
    if (idx < SUB * THIST) {
        int j = idx % THIST, s = idx / THIST;
        float acc = 0.f;
        for (int b = 0; b < BNUM; ++b) {
            float tau = expf((float)b);
            float tt = (float)j / tau;
            acc += W_ns_prop[s * 3 + b] * tt * expf(-tt);
        }
        propk[s * THIST + j] = acc;
    }
}

// ---------------------------------------------------------------------------
// k_insum: segment-sum per timestep -> transposed [s][t] layouts + fused
// somatic synaptic drive syn_sT[c][t].
// ---------------------------------------------------------------------------
__global__ void k_insum(const float* __restrict__ Se, const float* __restrict__ Si,
                        const int* __restrict__ ae, const int* __restrict__ ai,
                        const float* __restrict__ W_s_syn,
                        float* __restrict__ in_eT, float* __restrict__ in_iT,
                        float* __restrict__ syn_sT,
                        int T, int E, int I)
{
    int t = blockIdx.x;
    __shared__ float le[SUB], li[SUB];
    if (threadIdx.x < SUB) { le[threadIdx.x] = 0.f; li[threadIdx.x] = 0.f; }
    __syncthreads();
    for (int e = threadIdx.x; e < E; e += blockDim.x) {
        float v = Se[(size_t)t * E + e];
        if (v != 0.f) atomicAdd(&le[ae[e]], v);
    }
    for (int i = threadIdx.x; i < I; i += blockDim.x) {
        float v = Si[(size_t)t * I + i];
        if (v != 0.f) atomicAdd(&li[ai[i]], v);
    }
    __syncthreads();
    int s = threadIdx.x;
    if (s < SUB) {
        in_eT[(size_t)s * T + t] = le[s];
        in_iT[(size_t)s * T + t] = li[s];
        if (s >= 1)
            syn_sT[(size_t)(s - 1) * T + t] =
                le[s] * W_s_syn[s * 2 + 0] + li[s] * W_s_syn[s * 2 + 1];
    }
}

// ---------------------------------------------------------------------------
// k_conv: 200-tap causal conv on transposed layouts.
// ---------------------------------------------------------------------------
__global__ void k_conv(const float* __restrict__ in_eT, const float* __restrict__ in_iT,
                       const float* __restrict__ ke, const float* __restrict__ ki,
                       float* __restrict__ syn_nsT, int T)
{
    int idx = blockIdx.x * blockDim.x + threadIdx.x;
    if (idx >= SUB * T) return;
    int s = idx / T, t = idx % T;
    float acc = 0.f;
    int jmax = min(TSYN - 1, t);
    for (int j = 0; j <= jmax; ++j)
        acc += in_eT[(size_t)s * T + t - j] * ke[s * TSYN + j]
             + in_iT[(size_t)s * T + t - j] * ki[s * TSYN + j];
    syn_nsT[idx] = acc;
}

// ---------------------------------------------------------------------------
// k_spk: serial spike recurrence, one wave. Z state = low 19 bits of the
// wave ballot (wave-uniform SGPR); coupling dot = 19 branchless bit-tests
// (bit-identical to R2/R4). NO per-step global stores: z masks + x rows are
// buffered in LDS and bulk-stored (coalesced) at each chunk boundary.
// ---------------------------------------------------------------------------
__global__ __launch_bounds__(64) void k_spk(const float* __restrict__ syn_sT,
                      const float* __restrict__ Theta_s, const float* __restrict__ spike_decay,
                      const float* __restrict__ C_den, const float* __restrict__ W_s_prop,
                      float* __restrict__ Zout, float* __restrict__ Xout, int T)
{
    __shared__ float S[NC * CHSP];      // staged syn input
    __shared__ float SX[NC * CHSP];     // buffered x output
    __shared__ unsigned ZM[CHS];        // buffered z ballot masks
    int lane = threadIdx.x;
    int c = lane;
    bool act = c < NC;
    float M[NC];
    #pragma unroll
    for (int j = 0; j < NC; ++j)
        M[j] = act ? C_den[(c + 1) * SUB + (j + 1)] * W_s_prop[j] : 0.f;
    float theta = act ? Theta_s[c] : 0.f;
    float decay = act ? spike_decay[c] : 0.f;

    float x = 0.f;
    unsigned zlo = 0u;   // ballot low 32 bits; bits 0..18 = Z state
    for (int t0 = 0; t0 < T; t0 += CHS) {
        int len = min(CHS, T - t0);
        __syncthreads();
        for (int r = lane; r < (NC * CHS) / 4; r += 64) {
            int e = r * 4;
            int cc = e >> 8;           // e / CHS
            int tl = e & (CHS - 1);    // e % CHS
            if (tl < len) {
                float4 v = *(const float4*)(syn_sT + (size_t)cc * T + t0 + tl);
                *(float4*)(&S[cc * CHSP + tl]) = v;
            }
        }
        __syncthreads();
        float4 cur = act ? *(float4*)(&S[c * CHSP]) : make_float4(0.f, 0.f, 0.f, 0.f);
        for (int g = 0; g < len; g += 4) {
            float4 nxt = (act && g + 4 < len) ? *(float4*)(&S[c * CHSP + g + 4]) : cur;
            #pragma unroll
            for (int q = 0; q < 4; ++q) {
                float syn = (q == 0) ? cur.x : (q == 1) ? cur.y : (q == 2) ? cur.z : cur.w;
                float P = 0.f;
                #pragma unroll
                for (int j = 0; j < NC; ++j) {          // branchless, compile-time shifts
                    float b = (float)((zlo >> j) & 1u);
                    P = fmaf(b, M[j], P);               // exact: b in {0,1}
                }
                float xin = fmaf(x, decay, syn);
                xin += P;
                xin += theta;
                int tl = g + q;
                if (t0 + tl < T) {
                    bool zb = xin >= 0.f;
                    zlo = (unsigned)__ballot(zb);
                    x = zb ? 0.f : xin;
                    if (act) SX[c * CHSP + tl] = x;     // fire-and-forget LDS
                    if (lane == NC) ZM[tl] = zlo;       // one lane writes the mask
                }
            }
            cur = nxt;
        }
        __syncthreads();
        // bulk coalesced store of this chunk's Z and X ([t][c] row-major)
        for (int r = lane; r < len * NC; r += 64) {
            int tl = r / NC;
            int cc = r - tl * NC;
            size_t o = (size_t)(t0 + tl) * NC + cc;
            Zout[o] = (float)((ZM[tl] >> cc) & 1u);
            Xout[o] = SX[cc * CHSP + tl];
        }
    }
}

// ---------------------------------------------------------------------------
// k_pz: PZ_T[s][u] = sum_c Z[u,c] * C_den[s, c+1]
// ---------------------------------------------------------------------------
__global__ void k_pz(const float* __restrict__ Z, const float* __restrict__ C_den,
                     float* __restrict__ PZ_T, int T)
{
    int idx = blockIdx.x * blockDim.x + threadIdx.x;
    if (idx >= SUB * T) return;
    int s = idx / T, u = idx % T;
    float acc = 0.f;
    #pragma unroll
    for (int c = 0; c < NC; ++c)
        acc += Z[(size_t)u * NC + c] * C_den[s * SUB + c + 1];
    PZ_T[idx] = acc;
}

// ---------------------------------------------------------------------------
// k_A: A_T[s][t] = syn_ns + Theta_ns + f_prop (+ f_hist for s>=1)
// ---------------------------------------------------------------------------
__global__ void k_A(const float* __restrict__ syn_nsT, const float* __restrict__ PZ_T,
                    const float* __restrict__ Z, const float* __restrict__ histk,
                    const float* __restrict__ propk, const float* __restrict__ Theta_ns,
                    float* __restrict__ A_T, int T)
{
    int idx = blockIdx.x * blockDim.x + threadIdx.x;
    if (idx >= SUB * T) return;
    int s = idx / T, t = idx % T;
    float acc = syn_nsT[idx] + Theta_ns[s];
    int jmax = min(THIST - 1, t - 1);
    for (int j = 0; j <= jmax; ++j)
        acc += propk[s * THIST + j] * PZ_T[(size_t)s * T + t - 1 - j];
    if (s > 0) {
        int c = s - 1;
        for (int j = 0; j <= jmax; ++j)
            acc += histk[c * THIST + j] * Z[(size_t)(t - 1 - j) * NC + c];
    }
    A_T[idx] = acc;
}

// ---------------------------------------------------------------------------
// k_y: serial Y recurrence, one wave. Cross-lane exchange = one LDS round
// trip per step (ds_write y, 5 broadcast ds_read_b128). NO per-step global
// stores: y rows buffered in LDS, bulk-stored at chunk boundaries.
// ---------------------------------------------------------------------------
__global__ __launch_bounds__(64) void k_y(const float* __restrict__ A_T,
                    const float* __restrict__ C_den, const float* __restrict__ W_ns_sub,
                    const float* __restrict__ V_o,
                    float* __restrict__ Vout, float* __restrict__ Yout, int T)
{
    __shared__ float S[SUB * CHSP];     // staged A input
    __shared__ float SY[SUB * CHSP];    // buffered y output
    __shared__ __align__(16) float ybc[64];
    int lane = threadIdx.x;
    int s = lane;
    bool act = s < SUB;
    float Crow[SUB];
    #pragma unroll
    for (int j = 0; j < SUB; ++j)
        Crow[j] = act ? C_den[s * SUB + j] : 0.f;
    float wsub = act ? W_ns_sub[s] : 0.f;
    float vo = V_o[0];

    ybc[lane] = 0.f;
    __syncthreads();

    for (int t0 = 0; t0 < T; t0 += CHS) {
        int len = min(CHS, T - t0);
        __syncthreads();
        for (int r = lane; r < (SUB * CHS) / 4; r += 64) {
            int e = r * 4;
            int cc = e >> 8;
            int tl = e & (CHS - 1);
            if (tl < len) {
                float4 v = *(const float4*)(A_T + (size_t)cc * T + t0 + tl);
                *(float4*)(&S[cc * CHSP + tl]) = v;
            }
        }
        __syncthreads();
        float4 cur = act ? *(float4*)(&S[s * CHSP]) : make_float4(0.f, 0.f, 0.f, 0.f);
        for (int g = 0; g < len; g += 4) {
            float4 nxt = (act && g + 4 < len) ? *(float4*)(&S[s * CHSP + g + 4]) : cur;
            #pragma unroll
            for (int q = 0; q < 4; ++q) {
                float a = (q == 0) ? cur.x : (q == 1) ? cur.y : (q == 2) ? cur.z : cur.w;
                // broadcast read of y(t-1) vector (5x ds_read_b128, one wait)
                __builtin_amdgcn_wave_barrier();
                float4 Y0 = *(const float4*)(&ybc[0]);
                float4 Y1 = *(const float4*)(&ybc[4]);
                float4 Y2 = *(const float4*)(&ybc[8]);
                float4 Y3 = *(const float4*)(&ybc[12]);
                float4 Y4 = *(const float4*)(&ybc[16]);
                float u0 = a, u1 = 0.f, u2 = 0.f, u3 = 0.f;
                u0 += Crow[0]  * Y0.x;  u1 += Crow[1]  * Y0.y;
                u2 += Crow[2]  * Y0.z;  u3 += Crow[3]  * Y0.w;
                u0 += Crow[4]  * Y1.x;  u1 += Crow[5]  * Y1.y;
                u2 += Crow[6]  * Y1.z;  u3 += Crow[7]  * Y1.w;
                u0 += Crow[8]  * Y2.x;  u1 += Crow[9]  * Y2.y;
                u2 += Crow[10] * Y2.z;  u3 += Crow[11] * Y2.w;
                u0 += Crow[12] * Y3.x;  u1 += Crow[13] * Y3.y;
                u2 += Crow[14] * Y3.z;  u3 += Crow[15] * Y3.w;
                u0 += Crow[16] * Y4.x;  u1 += Crow[17] * Y4.y;
                u2 += Crow[18] * Y4.z;  u3 += Crow[19] * Y4.w;
                float u = (u0 + u1) + (u2 + u3);
                int tl = g + q;
                if (t0 + tl < T) {
                    float y = wsub / (1.f + __expf(-u));   // lanes>=20 -> 0
                    __builtin_amdgcn_wave_barrier();
                    ybc[lane] = y;
                    if (act) SY[s * CHSP + tl] = y;        // fire-and-forget LDS
                }
            }
            cur = nxt;
        }
        __syncthreads();
        // bulk coalesced store of this chunk's V and Y
        for (int tl = lane; tl < len; tl += 64)
            Vout[t0 + tl] = SY[0 * CHSP + tl] + vo;
        for (int r = lane; r < len * NC; r += 64) {
            int tl = r / NC;
            int cc = r - tl * NC;
            Yout[(size_t)(t0 + tl) * NC + cc] = SY[(cc + 1) * CHSP + tl];
        }
    }
}

// ---------------------------------------------------------------------------
extern "C" void kernel_launch(void* const* d_in, const int* in_sizes, int n_in,
                              void* d_out, int out_size, void* d_ws, size_t ws_size,
                              hipStream_t stream)
{
    const float* S_e          = (const float*)d_in[0];
    const float* S_i          = (const float*)d_in[1];
    const float* C_den        = (const float*)d_in[2];
    const float* C_syn_e      = (const float*)d_in[3];
    const float* C_syn_i      = (const float*)d_in[4];
    const float* W_s_syn      = (const float*)d_in[5];
    const float* W_ns_syn     = (const float*)d_in[6];
    const float* Delta_ns_syn = (const float*)d_in[7];
    const float* W_ns_sub     = (const float*)d_in[8];
    const float* V_o          = (const float*)d_in[9];
    const float* Theta_s      = (const float*)d_in[10];
    const float* Theta_ns     = (const float*)d_in[11];
    const float* W_ns_hist    = (const float*)d_in[12];
    const float* W_s_prop     = (const float*)d_in[13];
    const float* W_ns_prop    = (const float*)d_in[14];
    const float* spike_decay  = (const float*)d_in[15];

    int E = in_sizes[3] / SUB;
    int I = in_sizes[4] / SUB;
    int T = in_sizes[0] / E;

    float* out  = (float*)d_out;
    float* Vout = out;                           // [T]
    float* Yout = out + (size_t)T;               // [T, 19]
    float* Zout = out + (size_t)T * (1 + NC);    // [T, 19]
    float* Xout = out + (size_t)T * (1 + 2*NC);  // [T, 19]

    float* w       = (float*)d_ws;
    float* in_eT   = w;  w += (size_t)SUB * T;   // aliased as A_T after k_conv
    float* in_iT   = w;  w += (size_t)SUB * T;
    float* syn_sT  = w;  w += (size_t)NC * T;
    float* syn_nsT = w;  w += (size_t)SUB * T;
    float* PZ_T    = w;  w += (size_t)SUB * T;
    float* ke      = w;  w += SUB * TSYN;
    float* ki      = w;  w += SUB * TSYN;
    float* histk   = w;  w += NC * THIST;
    float* propk   = w;  w += SUB * THIST;
    int*   ae      = (int*)w;
    int*   ai      = ae + E;
    float* A_T     = in_eT;   // in_eT dead after k_conv

    int nprep = E + I + SUB * 2 * TSYN + NC * THIST + SUB * THIST;
    hipLaunchKernelGGL(k_prep, dim3((nprep + 255) / 256), dim3(256), 0, stream,
                       C_syn_e, C_syn_i, W_ns_syn, Delta_ns_syn, W_ns_hist, W_ns_prop,
                       ae, ai, ke, ki, histk, propk, E, I);
    hipLaunchKernelGGL(k_insum, dim3(T), dim3(256), 0, stream,
                       S_e, S_i, ae, ai, W_s_syn, in_eT, in_iT, syn_sT, T, E, I);
    hipLaunchKernelGGL(k_conv, dim3((SUB * T + 255) / 256), dim3(256), 0, stream,
                       in_eT, in_iT, ke, ki, syn_nsT, T);
    hipLaunchKernelGGL(k_spk, dim3(1), dim3(64), 0, stream,
                       syn_sT, Theta_s, spike_decay, C_den, W_s_prop, Zout, Xout, T);
    hipLaunchKernelGGL(k_pz, dim3((SUB * T + 255) / 256), dim3(256), 0, stream,
                       Zout, C_den, PZ_T, T);
    hipLaunchKernelGGL(k_A, dim3((SUB * T + 255) / 256), dim3(256), 0, stream,
                       syn_nsT, PZ_T, Zout, histk, propk, Theta_ns, A_T, T);
    hipLaunchKernelGGL(k_y, dim3(1), dim3(64), 0, stream,
                       A_T, C_den, W_ns_sub, V_o, Vout, Yout, T);
}

// Round 6
// 457.539 us; speedup vs baseline: 20.4827x; 9.2948x over previous
//
#include <hip/hip_runtime.h>
#include <math.h>

#define SUB 20       // sub_no
#define NC 19        // sub_no - 1
#define TSYN 200
#define THIST 50
#define BNUM 3
#define CHS 256      // serial-kernel LDS staging chunk (power of 2, mult of 4)
#define CHSP (CHS+4) // padded stride for float4-staged input rows
#define LSEG 256     // live segment length per block (mult of 4)
#define WARM 192     // speculative warm-up steps (mult of 4)

// ---------------------------------------------------------------------------
// k_prep: assignment indices from one-hot C_syn, plus the three alpha-basis
// kernels (syn with delta shift, hist, prop).
// ---------------------------------------------------------------------------
__global__ void k_prep(const float* __restrict__ C_syn_e, const float* __restrict__ C_syn_i,
                       const float* __restrict__ W_ns_syn, const float* __restrict__ Delta_ns_syn,
                       const float* __restrict__ W_ns_hist, const float* __restrict__ W_ns_prop,
                       int* __restrict__ ae, int* __restrict__ ai,
                       float* __restrict__ ke, float* __restrict__ ki,
                       float* __restrict__ histk, float* __restrict__ propk,
                       int E, int I)
{
    int idx = blockIdx.x * blockDim.x + threadIdx.x;
    if (idx < E) {
        int a = 0;
        for (int s = 0; s < SUB; ++s) if (C_syn_e[(size_t)s * E + idx] != 0.f) a = s;
        ae[idx] = a;
        return;
    }
    idx -= E;
    if (idx < I) {
        int a = 0;
        for (int s = 0; s < SUB; ++s) if (C_syn_i[(size_t)s * I + idx] != 0.f) a = s;
        ai[idx] = a;
        return;
    }
    idx -= I;
    if (idx < SUB * 2 * TSYN) {
        int j   = idx % TSYN;
        int rem = idx / TSYN;
        int c2  = rem & 1;
        int s   = rem >> 1;
        float delta = expf(Delta_ns_syn[s * 2 + c2]);
        float ts = fmaxf((float)j - delta, 0.f);
        float acc = 0.f;
        for (int b = 0; b < BNUM; ++b) {
            float tau = expf((float)b);
            float tt = ts / tau;
            acc += W_ns_syn[s * 6 + b * 2 + c2] * tt * expf(-tt);
        }
        if (c2 == 0) ke[s * TSYN + j] = acc; else ki[s * TSYN + j] = acc;
        return;
    }
    idx -= SUB * 2 * TSYN;
    if (idx < NC * THIST) {
        int j = idx % THIST, c = idx / THIST;
        float acc = 0.f;
        for (int b = 0; b < BNUM; ++b) {
            float tau = expf((float)b);
            float tt = (float)j / tau;
            acc += W_ns_hist[c * 3 + b] * tt * expf(-tt);
        }
        histk[c * THIST + j] = acc;
        return;
    }
    idx -= NC * THIST;
    if (idx < SUB * THIST) {
        int j = idx % THIST, s = idx / THIST;
        float acc = 0.f;
        for (int b = 0; b < BNUM; ++b) {
            float tau = expf((float)b);
            float tt = (float)j / tau;
            acc += W_ns_prop[s * 3 + b] * tt * expf(-tt);
        }
        propk[s * THIST + j] = acc;
    }
}

// ---------------------------------------------------------------------------
// k_insum: segment-sum per timestep -> transposed [s][t] layouts + fused
// somatic synaptic drive syn_sT[c][t].
// ---------------------------------------------------------------------------
__global__ void k_insum(const float* __restrict__ Se, const float* __restrict__ Si,
                        const int* __restrict__ ae, const int* __restrict__ ai,
                        const float* __restrict__ W_s_syn,
                        float* __restrict__ in_eT, float* __restrict__ in_iT,
                        float* __restrict__ syn_sT,
                        int T, int E, int I)
{
    int t = blockIdx.x;
    __shared__ float le[SUB], li[SUB];
    if (threadIdx.x < SUB) { le[threadIdx.x] = 0.f; li[threadIdx.x] = 0.f; }
    __syncthreads();
    for (int e = threadIdx.x; e < E; e += blockDim.x) {
        float v = Se[(size_t)t * E + e];
        if (v != 0.f) atomicAdd(&le[ae[e]], v);
    }
    for (int i = threadIdx.x; i < I; i += blockDim.x) {
        float v = Si[(size_t)t * I + i];
        if (v != 0.f) atomicAdd(&li[ai[i]], v);
    }
    __syncthreads();
    int s = threadIdx.x;
    if (s < SUB) {
        in_eT[(size_t)s * T + t] = le[s];
        in_iT[(size_t)s * T + t] = li[s];
        if (s >= 1)
            syn_sT[(size_t)(s - 1) * T + t] =
                le[s] * W_s_syn[s * 2 + 0] + li[s] * W_s_syn[s * 2 + 1];
    }
}

// ---------------------------------------------------------------------------
// k_conv: 200-tap causal conv on transposed layouts.
// ---------------------------------------------------------------------------
__global__ void k_conv(const float* __restrict__ in_eT, const float* __restrict__ in_iT,
                       const float* __restrict__ ke, const float* __restrict__ ki,
                       float* __restrict__ syn_nsT, int T)
{
    int idx = blockIdx.x * blockDim.x + threadIdx.x;
    if (idx >= SUB * T) return;
    int s = idx / T, t = idx % T;
    float acc = 0.f;
    int jmax = min(TSYN - 1, t);
    for (int j = 0; j <= jmax; ++j)
        acc += in_eT[(size_t)s * T + t - j] * ke[s * TSYN + j]
             + in_iT[(size_t)s * T + t - j] * ki[s * TSYN + j];
    syn_nsT[idx] = acc;
}

// ---------------------------------------------------------------------------
// k_spk: spike recurrence, TIME-PARALLEL over 40 blocks. Block b owns
// t in [b*LSEG, b*LSEG+LSEG); it starts WARM steps earlier from x=0,z=0 —
// spike_decay<0.4 + exact spike resets make the state bit-identical to the
// true trajectory well before t0. Per-step math identical to R5 (ballot-bit
// coupling, branchless). Outputs buffered in LDS, bulk-stored per chunk.
// ---------------------------------------------------------------------------
__global__ __launch_bounds__(64) void k_spk(const float* __restrict__ syn_sT,
                      const float* __restrict__ Theta_s, const float* __restrict__ spike_decay,
                      const float* __restrict__ C_den, const float* __restrict__ W_s_prop,
                      float* __restrict__ Zout, float* __restrict__ Xout, int T)
{
    __shared__ float S[NC * CHSP];      // staged syn input ([c][tl], float4 rows)
    __shared__ float SX[CHS * SUB];     // buffered x ([tl][c], stride 20: conflict-free)
    __shared__ unsigned ZM[CHS];        // buffered z ballot masks
    int lane = threadIdx.x;
    int c = lane;
    bool act = c < NC;
    int t0 = blockIdx.x * LSEG;
    if (t0 >= T) return;
    int t1 = min(t0 + LSEG, T);
    int tw = max(0, t0 - WARM);

    float M[NC];
    #pragma unroll
    for (int j = 0; j < NC; ++j)
        M[j] = act ? C_den[(c + 1) * SUB + (j + 1)] * W_s_prop[j] : 0.f;
    float theta = act ? Theta_s[c] : 0.f;
    float decay = act ? spike_decay[c] : 0.f;

    float x = 0.f;
    unsigned zlo = 0u;   // ballot low 32 bits; bits 0..18 = Z state
    for (int tc = tw; tc < t1; tc += CHS) {
        int len = min(CHS, t1 - tc);     // always a multiple of 4
        __syncthreads();
        for (int r = lane; r < (NC * CHS) / 4; r += 64) {
            int e = r * 4;
            int cc = e >> 8;           // e / CHS
            int tl = e & (CHS - 1);    // e % CHS
            if (tl < len) {
                float4 v = *(const float4*)(syn_sT + (size_t)cc * T + tc + tl);
                *(float4*)(&S[cc * CHSP + tl]) = v;
            }
        }
        __syncthreads();
        float4 cur = act ? *(float4*)(&S[c * CHSP]) : make_float4(0.f, 0.f, 0.f, 0.f);
        for (int g = 0; g < len; g += 4) {
            float4 nxt = (act && g + 4 < len) ? *(float4*)(&S[c * CHSP + g + 4]) : cur;
            #pragma unroll
            for (int q = 0; q < 4; ++q) {
                float syn = (q == 0) ? cur.x : (q == 1) ? cur.y : (q == 2) ? cur.z : cur.w;
                float P = 0.f;
                #pragma unroll
                for (int j = 0; j < NC; ++j) {          // branchless bit-tests
                    float b = (float)((zlo >> j) & 1u);
                    P = fmaf(b, M[j], P);               // exact: b in {0,1}
                }
                float xin = fmaf(x, decay, syn);
                xin += P;
                xin += theta;
                bool zb = xin >= 0.f;
                zlo = (unsigned)__ballot(zb);
                x = zb ? 0.f : xin;
                int tl = g + q;
                if (act) SX[tl * SUB + c] = x;          // conflict-free LDS write
                if (lane == NC) ZM[tl] = zlo;
            }
            cur = nxt;
        }
        __syncthreads();
        if (tc + len > t0) {
            // bulk coalesced store of live part of this chunk
            for (int r = lane; r < len * NC; r += 64) {
                int tl = r / NC;
                int cc = r - tl * NC;
                int tg = tc + tl;
                if (tg >= t0) {
                    size_t o = (size_t)tg * NC + cc;
                    Zout[o] = (float)((ZM[tl] >> cc) & 1u);
                    Xout[o] = SX[tl * SUB + cc];
                }
            }
        }
    }
}

// ---------------------------------------------------------------------------
// k_pz: PZ_T[s][u] = sum_c Z[u,c] * C_den[s, c+1]
// ---------------------------------------------------------------------------
__global__ void k_pz(const float* __restrict__ Z, const float* __restrict__ C_den,
                     float* __restrict__ PZ_T, int T)
{
    int idx = blockIdx.x * blockDim.x + threadIdx.x;
    if (idx >= SUB * T) return;
    int s = idx / T, u = idx % T;
    float acc = 0.f;
    #pragma unroll
    for (int c = 0; c < NC; ++c)
        acc += Z[(size_t)u * NC + c] * C_den[s * SUB + c + 1];
    PZ_T[idx] = acc;
}

// ---------------------------------------------------------------------------
// k_A: A_T[s][t] = syn_ns + Theta_ns + f_prop (+ f_hist for s>=1)
// ---------------------------------------------------------------------------
__global__ void k_A(const float* __restrict__ syn_nsT, const float* __restrict__ PZ_T,
                    const float* __restrict__ Z, const float* __restrict__ histk,
                    const float* __restrict__ propk, const float* __restrict__ Theta_ns,
                    float* __restrict__ A_T, int T)
{
    int idx = blockIdx.x * blockDim.x + threadIdx.x;
    if (idx >= SUB * T) return;
    int s = idx / T, t = idx % T;
    float acc = syn_nsT[idx] + Theta_ns[s];
    int jmax = min(THIST - 1, t - 1);
    for (int j = 0; j <= jmax; ++j)
        acc += propk[s * THIST + j] * PZ_T[(size_t)s * T + t - 1 - j];
    if (s > 0) {
        int c = s - 1;
        for (int j = 0; j <= jmax; ++j)
            acc += histk[c * THIST + j] * Z[(size_t)(t - 1 - j) * NC + c];
    }
    A_T[idx] = acc;
}

// ---------------------------------------------------------------------------
// k_y: Y recurrence, TIME-PARALLEL over 40 blocks. Contraction (spectral
// radius ~0.75/step) makes WARM=192 warm-up error ~1e-24 — invisible on the
// smooth Y path. Per-step math identical to R5 (LDS ybc round-trip).
// ---------------------------------------------------------------------------
__global__ __launch_bounds__(64) void k_y(const float* __restrict__ A_T,
                    const float* __restrict__ C_den, const float* __restrict__ W_ns_sub,
                    const float* __restrict__ V_o,
                    float* __restrict__ Vout, float* __restrict__ Yout, int T)
{
    __shared__ float S[SUB * CHSP];     // staged A input
    __shared__ float SY[CHS * SUB];     // buffered y ([tl][s], stride 20)
    __shared__ __align__(16) float ybc[64];
    int lane = threadIdx.x;
    int s = lane;
    bool act = s < SUB;
    int t0 = blockIdx.x * LSEG;
    if (t0 >= T) return;
    int t1 = min(t0 + LSEG, T);
    int tw = max(0, t0 - WARM);

    float Crow[SUB];
    #pragma unroll
    for (int j = 0; j < SUB; ++j)
        Crow[j] = act ? C_den[s * SUB + j] : 0.f;
    float wsub = act ? W_ns_sub[s] : 0.f;
    float vo = V_o[0];

    ybc[lane] = 0.f;
    __syncthreads();

    for (int tc = tw; tc < t1; tc += CHS) {
        int len = min(CHS, t1 - tc);     // multiple of 4
        __syncthreads();
        for (int r = lane; r < (SUB * CHS) / 4; r += 64) {
            int e = r * 4;
            int cc = e >> 8;
            int tl = e & (CHS - 1);
            if (tl < len) {
                float4 v = *(const float4*)(A_T + (size_t)cc * T + tc + tl);
                *(float4*)(&S[cc * CHSP + tl]) = v;
            }
        }
        __syncthreads();
        float4 cur = act ? *(float4*)(&S[s * CHSP]) : make_float4(0.f, 0.f, 0.f, 0.f);
        for (int g = 0; g < len; g += 4) {
            float4 nxt = (act && g + 4 < len) ? *(float4*)(&S[s * CHSP + g + 4]) : cur;
            #pragma unroll
            for (int q = 0; q < 4; ++q) {
                float a = (q == 0) ? cur.x : (q == 1) ? cur.y : (q == 2) ? cur.z : cur.w;
                __builtin_amdgcn_wave_barrier();
                float4 Y0 = *(const float4*)(&ybc[0]);
                float4 Y1 = *(const float4*)(&ybc[4]);
                float4 Y2 = *(const float4*)(&ybc[8]);
                float4 Y3 = *(const float4*)(&ybc[12]);
                float4 Y4 = *(const float4*)(&ybc[16]);
                float u0 = a, u1 = 0.f, u2 = 0.f, u3 = 0.f;
                u0 += Crow[0]  * Y0.x;  u1 += Crow[1]  * Y0.y;
                u2 += Crow[2]  * Y0.z;  u3 += Crow[3]  * Y0.w;
                u0 += Crow[4]  * Y1.x;  u1 += Crow[5]  * Y1.y;
                u2 += Crow[6]  * Y1.z;  u3 += Crow[7]  * Y1.w;
                u0 += Crow[8]  * Y2.x;  u1 += Crow[9]  * Y2.y;
                u2 += Crow[10] * Y2.z;  u3 += Crow[11] * Y2.w;
                u0 += Crow[12] * Y3.x;  u1 += Crow[13] * Y3.y;
                u2 += Crow[14] * Y3.z;  u3 += Crow[15] * Y3.w;
                u0 += Crow[16] * Y4.x;  u1 += Crow[17] * Y4.y;
                u2 += Crow[18] * Y4.z;  u3 += Crow[19] * Y4.w;
                float u = (u0 + u1) + (u2 + u3);
                float y = wsub / (1.f + __expf(-u));   // lanes>=20 -> 0
                __builtin_amdgcn_wave_barrier();
                ybc[lane] = y;
                int tl = g + q;
                if (act) SY[tl * SUB + s] = y;         // conflict-free LDS write
            }
            cur = nxt;
        }
        __syncthreads();
        if (tc + len > t0) {
            for (int r = lane; r < len * SUB; r += 64) {
                int tl = r / SUB;
                int cc = r - tl * SUB;
                int tg = tc + tl;
                if (tg >= t0) {
                    float y = SY[r];
                    if (cc == 0) Vout[tg] = y + vo;
                    else         Yout[(size_t)tg * NC + (cc - 1)] = y;
                }
            }
        }
    }
}

// ---------------------------------------------------------------------------
extern "C" void kernel_launch(void* const* d_in, const int* in_sizes, int n_in,
                              void* d_out, int out_size, void* d_ws, size_t ws_size,
                              hipStream_t stream)
{
    const float* S_e          = (const float*)d_in[0];
    const float* S_i          = (const float*)d_in[1];
    const float* C_den        = (const float*)d_in[2];
    const float* C_syn_e      = (const float*)d_in[3];
    const float* C_syn_i      = (const float*)d_in[4];
    const float* W_s_syn      = (const float*)d_in[5];
    const float* W_ns_syn     = (const float*)d_in[6];
    const float* Delta_ns_syn = (const float*)d_in[7];
    const float* W_ns_sub     = (const float*)d_in[8];
    const float* V_o          = (const float*)d_in[9];
    const float* Theta_s      = (const float*)d_in[10];
    const float* Theta_ns     = (const float*)d_in[11];
    const float* W_ns_hist    = (const float*)d_in[12];
    const float* W_s_prop     = (const float*)d_in[13];
    const float* W_ns_prop    = (const float*)d_in[14];
    const float* spike_decay  = (const float*)d_in[15];

    int E = in_sizes[3] / SUB;
    int I = in_sizes[4] / SUB;
    int T = in_sizes[0] / E;

    float* out  = (float*)d_out;
    float* Vout = out;                           // [T]
    float* Yout = out + (size_t)T;               // [T, 19]
    float* Zout = out + (size_t)T * (1 + NC);    // [T, 19]
    float* Xout = out + (size_t)T * (1 + 2*NC);  // [T, 19]

    float* w       = (float*)d_ws;
    float* in_eT   = w;  w += (size_t)SUB * T;   // aliased as A_T after k_conv
    float* in_iT   = w;  w += (size_t)SUB * T;
    float* syn_sT  = w;  w += (size_t)NC * T;
    float* syn_nsT = w;  w += (size_t)SUB * T;
    float* PZ_T    = w;  w += (size_t)SUB * T;
    float* ke      = w;  w += SUB * TSYN;
    float* ki      = w;  w += SUB * TSYN;
    float* histk   = w;  w += NC * THIST;
    float* propk   = w;  w += SUB * THIST;
    int*   ae      = (int*)w;
    int*   ai      = ae + E;
    float* A_T     = in_eT;   // in_eT dead after k_conv

    int NB = (T + LSEG - 1) / LSEG;   // time-parallel blocks for serial kernels

    int nprep = E + I + SUB * 2 * TSYN + NC * THIST + SUB * THIST;
    hipLaunchKernelGGL(k_prep, dim3((nprep + 255) / 256), dim3(256), 0, stream,
                       C_syn_e, C_syn_i, W_ns_syn, Delta_ns_syn, W_ns_hist, W_ns_prop,
                       ae, ai, ke, ki, histk, propk, E, I);
    hipLaunchKernelGGL(k_insum, dim3(T), dim3(256), 0, stream,
                       S_e, S_i, ae, ai, W_s_syn, in_eT, in_iT, syn_sT, T, E, I);
    hipLaunchKernelGGL(k_conv, dim3((SUB * T + 255) / 256), dim3(256), 0, stream,
                       in_eT, in_iT, ke, ki, syn_nsT, T);
    hipLaunchKernelGGL(k_spk, dim3(NB), dim3(64), 0, stream,
                       syn_sT, Theta_s, spike_decay, C_den, W_s_prop, Zout, Xout, T);
    hipLaunchKernelGGL(k_pz, dim3((SUB * T + 255) / 256), dim3(256), 0, stream,
                       Zout, C_den, PZ_T, T);
    hipLaunchKernelGGL(k_A, dim3((SUB * T + 255) / 256), dim3(256), 0, stream,
                       syn_nsT, PZ_T, Zout, histk, propk, Theta_ns, A_T, T);
    hipLaunchKernelGGL(k_y, dim3(NB), dim3(64), 0, stream,
                       A_T, C_den, W_ns_sub, V_o, Vout, Yout, T);
}

// Round 7
// 304.940 us; speedup vs baseline: 30.7327x; 1.5004x over previous
//
#include <hip/hip_runtime.h>
#include <math.h>

#define SUB 20       // sub_no
#define NC 19        // sub_no - 1
#define TSYN 200
#define THIST 50
#define BNUM 3
#define CHS 256      // serial-kernel LDS staging chunk (power of 2, mult of 4)
#define CHSP (CHS+4) // padded stride for float4-staged input rows
#define LSEG 64      // live segment length per block (mult of 4)
#define WARMS 96     // spike warm-up steps (mult of 4): 0.4^k decay + exact resets
#define WARMY 64     // Y warm-up steps (mult of 4): contraction <=0.75/step

// ---------------------------------------------------------------------------
// k_prep: assignment indices from one-hot C_syn, plus the three alpha-basis
// kernels (syn with delta shift, hist, prop).
// ---------------------------------------------------------------------------
__global__ void k_prep(const float* __restrict__ C_syn_e, const float* __restrict__ C_syn_i,
                       const float* __restrict__ W_ns_syn, const float* __restrict__ Delta_ns_syn,
                       const float* __restrict__ W_ns_hist, const float* __restrict__ W_ns_prop,
                       int* __restrict__ ae, int* __restrict__ ai,
                       float* __restrict__ ke, float* __restrict__ ki,
                       float* __restrict__ histk, float* __restrict__ propk,
                       int E, int I)
{
    int idx = blockIdx.x * blockDim.x + threadIdx.x;
    if (idx < E) {
        int a = 0;
        for (int s = 0; s < SUB; ++s) if (C_syn_e[(size_t)s * E + idx] != 0.f) a = s;
        ae[idx] = a;
        return;
    }
    idx -= E;
    if (idx < I) {
        int a = 0;
        for (int s = 0; s < SUB; ++s) if (C_syn_i[(size_t)s * I + idx] != 0.f) a = s;
        ai[idx] = a;
        return;
    }
    idx -= I;
    if (idx < SUB * 2 * TSYN) {
        int j   = idx % TSYN;
        int rem = idx / TSYN;
        int c2  = rem & 1;
        int s   = rem >> 1;
        float delta = expf(Delta_ns_syn[s * 2 + c2]);
        float ts = fmaxf((float)j - delta, 0.f);
        float acc = 0.f;
        for (int b = 0; b < BNUM; ++b) {
            float tau = expf((float)b);
            float tt = ts / tau;
            acc += W_ns_syn[s * 6 + b * 2 + c2] * tt * expf(-tt);
        }
        if (c2 == 0) ke[s * TSYN + j] = acc; else ki[s * TSYN + j] = acc;
        return;
    }
    idx -= SUB * 2 * TSYN;
    if (idx < NC * THIST) {
        int j = idx % THIST, c = idx / THIST;
        float acc = 0.f;
        for (int b = 0; b < BNUM; ++b) {
            float tau = expf((float)b);
            float tt = (float)j / tau;
            acc += W_ns_hist[c * 3 + b] * tt * expf(-tt);
        }
        histk[c * THIST + j] = acc;
        return;
    }
    idx -= NC * THIST;
    if (idx < SUB * THIST) {
        int j = idx % THIST, s = idx / THIST;
        float acc = 0.f;
        for (int b = 0; b < BNUM; ++b) {
            float tau = expf((float)b);
            float tt = (float)j / tau;
            acc += W_ns_prop[s * 3 + b] * tt * expf(-tt);
        }
        propk[s * THIST + j] = acc;
    }
}

// ---------------------------------------------------------------------------
// k_insum: segment-sum per timestep (float4 spike loads) -> transposed
// [s][t] layouts + fused somatic synaptic drive syn_sT[c][t].
// ---------------------------------------------------------------------------
__global__ void k_insum(const float* __restrict__ Se, const float* __restrict__ Si,
                        const int* __restrict__ ae, const int* __restrict__ ai,
                        const float* __restrict__ W_s_syn,
                        float* __restrict__ in_eT, float* __restrict__ in_iT,
                        float* __restrict__ syn_sT,
                        int T, int E, int I)
{
    int t = blockIdx.x;
    __shared__ float le[SUB], li[SUB];
    if (threadIdx.x < SUB) { le[threadIdx.x] = 0.f; li[threadIdx.x] = 0.f; }
    __syncthreads();
    const float* Ser = Se + (size_t)t * E;
    const float* Sir = Si + (size_t)t * I;
    int E4 = E >> 2, I4 = I >> 2;
    for (int e4 = threadIdx.x; e4 < E4; e4 += blockDim.x) {
        float4 v = *(const float4*)(Ser + 4 * e4);
        if (v.x != 0.f) atomicAdd(&le[ae[4 * e4 + 0]], v.x);
        if (v.y != 0.f) atomicAdd(&le[ae[4 * e4 + 1]], v.y);
        if (v.z != 0.f) atomicAdd(&le[ae[4 * e4 + 2]], v.z);
        if (v.w != 0.f) atomicAdd(&le[ae[4 * e4 + 3]], v.w);
    }
    for (int e = 4 * E4 + threadIdx.x; e < E; e += blockDim.x) {
        float v = Ser[e];
        if (v != 0.f) atomicAdd(&le[ae[e]], v);
    }
    for (int i4 = threadIdx.x; i4 < I4; i4 += blockDim.x) {
        float4 v = *(const float4*)(Sir + 4 * i4);
        if (v.x != 0.f) atomicAdd(&li[ai[4 * i4 + 0]], v.x);
        if (v.y != 0.f) atomicAdd(&li[ai[4 * i4 + 1]], v.y);
        if (v.z != 0.f) atomicAdd(&li[ai[4 * i4 + 2]], v.z);
        if (v.w != 0.f) atomicAdd(&li[ai[4 * i4 + 3]], v.w);
    }
    for (int i = 4 * I4 + threadIdx.x; i < I; i += blockDim.x) {
        float v = Sir[i];
        if (v != 0.f) atomicAdd(&li[ai[i]], v);
    }
    __syncthreads();
    int s = threadIdx.x;
    if (s < SUB) {
        in_eT[(size_t)s * T + t] = le[s];
        in_iT[(size_t)s * T + t] = li[s];
        if (s >= 1)
            syn_sT[(size_t)(s - 1) * T + t] =
                le[s] * W_s_syn[s * 2 + 0] + li[s] * W_s_syn[s * 2 + 1];
    }
}

// ---------------------------------------------------------------------------
// k_conv: 200-tap causal conv, 4 outputs/thread via sliding-window registers
// (taps + data loads shared across the 4 outputs).
// ---------------------------------------------------------------------------
__global__ void k_conv(const float* __restrict__ in_eT, const float* __restrict__ in_iT,
                       const float* __restrict__ ke, const float* __restrict__ ki,
                       float* __restrict__ syn_nsT, int T)
{
    int T4 = T >> 2;
    int idx = blockIdx.x * blockDim.x + threadIdx.x;
    if (idx >= SUB * T4) return;
    int s = idx / T4, t4 = idx - s * T4;
    int t = 4 * t4;
    const float* be = in_eT + (size_t)s * T;
    const float* bi = in_iT + (size_t)s * T;
    const float* kes = ke + s * TSYN;
    const float* kis = ki + s * TSYN;
    float ea = be[t + 3], eb = be[t + 2], ec = be[t + 1], ed = be[t];
    float ia = bi[t + 3], ib = bi[t + 2], ic = bi[t + 1], id = bi[t];
    float a0 = 0.f, a1 = 0.f, a2 = 0.f, a3 = 0.f;
    int jend = min(TSYN - 1, t + 3);
    for (int j = 0; j <= jend; ++j) {
        float kej = kes[j], kij = kis[j];
        a3 = fmaf(ea, kej, a3); a3 = fmaf(ia, kij, a3);
        a2 = fmaf(eb, kej, a2); a2 = fmaf(ib, kij, a2);
        a1 = fmaf(ec, kej, a1); a1 = fmaf(ic, kij, a1);
        a0 = fmaf(ed, kej, a0); a0 = fmaf(id, kij, a0);
        ea = eb; eb = ec; ec = ed;
        ia = ib; ib = ic; ic = id;
        int off = t - 1 - j;
        ed = (off >= 0) ? be[off] : 0.f;
        id = (off >= 0) ? bi[off] : 0.f;
    }
    *(float4*)(syn_nsT + (size_t)s * T + t) = make_float4(a0, a1, a2, a3);
}

// ---------------------------------------------------------------------------
// k_spk: spike recurrence, TIME-PARALLEL (157 blocks x 64-step live segment,
// 96-step speculative warm-up from x=0,z=0; decay<0.4 + exact spike resets
// make state bit-identical well before t0). Per-step math identical to R5/R6.
// Outputs buffered in LDS; bulk store also writes transposed Z_T for k_pz/k_A.
// ---------------------------------------------------------------------------
__global__ __launch_bounds__(64) void k_spk(const float* __restrict__ syn_sT,
                      const float* __restrict__ Theta_s, const float* __restrict__ spike_decay,
                      const float* __restrict__ C_den, const float* __restrict__ W_s_prop,
                      float* __restrict__ Zout, float* __restrict__ Xout,
                      float* __restrict__ Z_T, int T)
{
    __shared__ float S[NC * CHSP];      // staged syn input ([c][tl], float4 rows)
    __shared__ float SX[CHS * SUB];     // buffered x ([tl][c], stride 20)
    __shared__ unsigned ZM[CHS];        // buffered z ballot masks
    int lane = threadIdx.x;
    int c = lane;
    bool act = c < NC;
    int t0 = blockIdx.x * LSEG;
    if (t0 >= T) return;
    int t1 = min(t0 + LSEG, T);
    int tw = max(0, t0 - WARMS);

    float M[NC];
    #pragma unroll
    for (int j = 0; j < NC; ++j)
        M[j] = act ? C_den[(c + 1) * SUB + (j + 1)] * W_s_prop[j] : 0.f;
    float theta = act ? Theta_s[c] : 0.f;
    float decay = act ? spike_decay[c] : 0.f;

    float x = 0.f;
    unsigned zlo = 0u;
    for (int tc = tw; tc < t1; tc += CHS) {
        int len = min(CHS, t1 - tc);     // multiple of 4
        __syncthreads();
        for (int r = lane; r < (NC * CHS) / 4; r += 64) {
            int e = r * 4;
            int cc = e >> 8;           // e / CHS
            int tl = e & (CHS - 1);    // e % CHS
            if (tl < len) {
                float4 v = *(const float4*)(syn_sT + (size_t)cc * T + tc + tl);
                *(float4*)(&S[cc * CHSP + tl]) = v;
            }
        }
        __syncthreads();
        float4 cur = act ? *(float4*)(&S[c * CHSP]) : make_float4(0.f, 0.f, 0.f, 0.f);
        for (int g = 0; g < len; g += 4) {
            float4 nxt = (act && g + 4 < len) ? *(float4*)(&S[c * CHSP + g + 4]) : cur;
            #pragma unroll
            for (int q = 0; q < 4; ++q) {
                float syn = (q == 0) ? cur.x : (q == 1) ? cur.y : (q == 2) ? cur.z : cur.w;
                float P = 0.f;
                #pragma unroll
                for (int j = 0; j < NC; ++j) {
                    float b = (float)((zlo >> j) & 1u);
                    P = fmaf(b, M[j], P);               // exact: b in {0,1}
                }
                float xin = fmaf(x, decay, syn);
                xin += P;
                xin += theta;
                bool zb = xin >= 0.f;
                zlo = (unsigned)__ballot(zb);
                x = zb ? 0.f : xin;
                int tl = g + q;
                if (act) SX[tl * SUB + c] = x;
                if (lane == NC) ZM[tl] = zlo;
            }
            cur = nxt;
        }
        __syncthreads();
        if (tc + len > t0) {
            for (int r = lane; r < len * NC; r += 64) {
                int tl = r / NC;
                int cc = r - tl * NC;
                int tg = tc + tl;
                if (tg >= t0) {
                    size_t o = (size_t)tg * NC + cc;
                    Zout[o] = (float)((ZM[tl] >> cc) & 1u);
                    Xout[o] = SX[tl * SUB + cc];
                }
            }
            // transposed copy for coalesced downstream reads
            for (int r = lane; r < len * NC; r += 64) {
                int cc = r / len;
                int tl = r - cc * len;
                int tg = tc + tl;
                if (tg >= t0)
                    Z_T[(size_t)cc * T + tg] = (float)((ZM[tl] >> cc) & 1u);
            }
        }
    }
}

// ---------------------------------------------------------------------------
// k_pz: PZ_T[s][u] = sum_c Z_T[c][u] * C_den[s, c+1]  (all loads coalesced)
// ---------------------------------------------------------------------------
__global__ void k_pz(const float* __restrict__ Z_T, const float* __restrict__ C_den,
                     float* __restrict__ PZ_T, int T)
{
    int idx = blockIdx.x * blockDim.x + threadIdx.x;
    if (idx >= SUB * T) return;
    int s = idx / T, u = idx - s * T;
    float acc = 0.f;
    #pragma unroll
    for (int c = 0; c < NC; ++c)
        acc += Z_T[(size_t)c * T + u] * C_den[s * SUB + c + 1];
    PZ_T[idx] = acc;
}

// ---------------------------------------------------------------------------
// k_A: A_T[s][t] = syn_ns + Theta_ns + f_prop (+ f_hist for s>=1),
// 4 outputs/thread via sliding-window registers over PZ_T / Z_T.
// ---------------------------------------------------------------------------
__global__ void k_A(const float* __restrict__ syn_nsT, const float* __restrict__ PZ_T,
                    const float* __restrict__ Z_T, const float* __restrict__ histk,
                    const float* __restrict__ propk, const float* __restrict__ Theta_ns,
                    float* __restrict__ A_T, int T)
{
    int T4 = T >> 2;
    int idx = blockIdx.x * blockDim.x + threadIdx.x;
    if (idx >= SUB * T4) return;
    int s = idx / T4, t4 = idx - s * T4;
    int t = 4 * t4;
    float4 sy = *(const float4*)(syn_nsT + (size_t)s * T + t);
    float th = Theta_ns[s];
    float u0 = sy.x + th, u1 = sy.y + th, u2 = sy.z + th, u3 = sy.w + th;
    // f_prop: taps propk[s][j] on PZ_T[s][t+q-1-j]
    {
        const float* bp = PZ_T + (size_t)s * T;
        const float* pk = propk + s * THIST;
        float pa = bp[t + 2], pb = bp[t + 1], pc = bp[t];
        float pd = (t - 1 >= 0) ? bp[t - 1] : 0.f;
        int jend = min(THIST - 1, t + 2);
        for (int j = 0; j <= jend; ++j) {
            float k = pk[j];
            u3 = fmaf(pa, k, u3); u2 = fmaf(pb, k, u2);
            u1 = fmaf(pc, k, u1); u0 = fmaf(pd, k, u0);
            pa = pb; pb = pc; pc = pd;
            int off = t - 2 - j;
            pd = (off >= 0) ? bp[off] : 0.f;
        }
    }
    // f_hist (s>=1): taps histk[s-1][j] on Z_T[s-1][t+q-1-j]
    if (s >= 1) {
        const float* bz = Z_T + (size_t)(s - 1) * T;
        const float* hk = histk + (s - 1) * THIST;
        float pa = bz[t + 2], pb = bz[t + 1], pc = bz[t];
        float pd = (t - 1 >= 0) ? bz[t - 1] : 0.f;
        int jend = min(THIST - 1, t + 2);
        for (int j = 0; j <= jend; ++j) {
            float k = hk[j];
            u3 = fmaf(pa, k, u3); u2 = fmaf(pb, k, u2);
            u1 = fmaf(pc, k, u1); u0 = fmaf(pd, k, u0);
            pa = pb; pb = pc; pc = pd;
            int off = t - 2 - j;
            pd = (off >= 0) ? bz[off] : 0.f;
        }
    }
    *(float4*)(A_T + (size_t)s * T + t) = make_float4(u0, u1, u2, u3);
}

// ---------------------------------------------------------------------------
// k_y: Y recurrence, TIME-PARALLEL (64-step live segment, 64-step warm-up;
// contraction <=0.75/step => warm-up error ~1e-8, invisible on smooth path).
// Per-step math identical to R5/R6 (LDS ybc round-trip).
// ---------------------------------------------------------------------------
__global__ __launch_bounds__(64) void k_y(const float* __restrict__ A_T,
                    const float* __restrict__ C_den, const float* __restrict__ W_ns_sub,
                    const float* __restrict__ V_o,
                    float* __restrict__ Vout, float* __restrict__ Yout, int T)
{
    __shared__ float S[SUB * CHSP];
    __shared__ float SY[CHS * SUB];
    __shared__ __align__(16) float ybc[64];
    int lane = threadIdx.x;
    int s = lane;
    bool act = s < SUB;
    int t0 = blockIdx.x * LSEG;
    if (t0 >= T) return;
    int t1 = min(t0 + LSEG, T);
    int tw = max(0, t0 - WARMY);

    float Crow[SUB];
    #pragma unroll
    for (int j = 0; j < SUB; ++j)
        Crow[j] = act ? C_den[s * SUB + j] : 0.f;
    float wsub = act ? W_ns_sub[s] : 0.f;
    float vo = V_o[0];

    ybc[lane] = 0.f;
    __syncthreads();

    for (int tc = tw; tc < t1; tc += CHS) {
        int len = min(CHS, t1 - tc);     // multiple of 4
        __syncthreads();
        for (int r = lane; r < (SUB * CHS) / 4; r += 64) {
            int e = r * 4;
            int cc = e >> 8;
            int tl = e & (CHS - 1);
            if (tl < len) {
                float4 v = *(const float4*)(A_T + (size_t)cc * T + tc + tl);
                *(float4*)(&S[cc * CHSP + tl]) = v;
            }
        }
        __syncthreads();
        float4 cur = act ? *(float4*)(&S[s * CHSP]) : make_float4(0.f, 0.f, 0.f, 0.f);
        for (int g = 0; g < len; g += 4) {
            float4 nxt = (act && g + 4 < len) ? *(float4*)(&S[s * CHSP + g + 4]) : cur;
            #pragma unroll
            for (int q = 0; q < 4; ++q) {
                float a = (q == 0) ? cur.x : (q == 1) ? cur.y : (q == 2) ? cur.z : cur.w;
                __builtin_amdgcn_wave_barrier();
                float4 Y0 = *(const float4*)(&ybc[0]);
                float4 Y1 = *(const float4*)(&ybc[4]);
                float4 Y2 = *(const float4*)(&ybc[8]);
                float4 Y3 = *(const float4*)(&ybc[12]);
                float4 Y4 = *(const float4*)(&ybc[16]);
                float u0 = a, u1 = 0.f, u2 = 0.f, u3 = 0.f;
                u0 += Crow[0]  * Y0.x;  u1 += Crow[1]  * Y0.y;
                u2 += Crow[2]  * Y0.z;  u3 += Crow[3]  * Y0.w;
                u0 += Crow[4]  * Y1.x;  u1 += Crow[5]  * Y1.y;
                u2 += Crow[6]  * Y1.z;  u3 += Crow[7]  * Y1.w;
                u0 += Crow[8]  * Y2.x;  u1 += Crow[9]  * Y2.y;
                u2 += Crow[10] * Y2.z;  u3 += Crow[11] * Y2.w;
                u0 += Crow[12] * Y3.x;  u1 += Crow[13] * Y3.y;
                u2 += Crow[14] * Y3.z;  u3 += Crow[15] * Y3.w;
                u0 += Crow[16] * Y4.x;  u1 += Crow[17] * Y4.y;
                u2 += Crow[18] * Y4.z;  u3 += Crow[19] * Y4.w;
                float u = (u0 + u1) + (u2 + u3);
                float y = wsub / (1.f + __expf(-u));   // lanes>=20 -> 0
                __builtin_amdgcn_wave_barrier();
                ybc[lane] = y;
                int tl = g + q;
                if (act) SY[tl * SUB + s] = y;
            }
            cur = nxt;
        }
        __syncthreads();
        if (tc + len > t0) {
            for (int r = lane; r < len * SUB; r += 64) {
                int tl = r / SUB;
                int cc = r - tl * SUB;
                int tg = tc + tl;
                if (tg >= t0) {
                    float y = SY[r];
                    if (cc == 0) Vout[tg] = y + vo;
                    else         Yout[(size_t)tg * NC + (cc - 1)] = y;
                }
            }
        }
    }
}

// ---------------------------------------------------------------------------
extern "C" void kernel_launch(void* const* d_in, const int* in_sizes, int n_in,
                              void* d_out, int out_size, void* d_ws, size_t ws_size,
                              hipStream_t stream)
{
    const float* S_e          = (const float*)d_in[0];
    const float* S_i          = (const float*)d_in[1];
    const float* C_den        = (const float*)d_in[2];
    const float* C_syn_e      = (const float*)d_in[3];
    const float* C_syn_i      = (const float*)d_in[4];
    const float* W_s_syn      = (const float*)d_in[5];
    const float* W_ns_syn     = (const float*)d_in[6];
    const float* Delta_ns_syn = (const float*)d_in[7];
    const float* W_ns_sub     = (const float*)d_in[8];
    const float* V_o          = (const float*)d_in[9];
    const float* Theta_s      = (const float*)d_in[10];
    const float* Theta_ns     = (const float*)d_in[11];
    const float* W_ns_hist    = (const float*)d_in[12];
    const float* W_s_prop     = (const float*)d_in[13];
    const float* W_ns_prop    = (const float*)d_in[14];
    const float* spike_decay  = (const float*)d_in[15];

    int E = in_sizes[3] / SUB;
    int I = in_sizes[4] / SUB;
    int T = in_sizes[0] / E;

    float* out  = (float*)d_out;
    float* Vout = out;                           // [T]
    float* Yout = out + (size_t)T;               // [T, 19]
    float* Zout = out + (size_t)T * (1 + NC);    // [T, 19]
    float* Xout = out + (size_t)T * (1 + 2*NC);  // [T, 19]

    float* w       = (float*)d_ws;
    float* in_eT   = w;  w += (size_t)SUB * T;   // dead after k_conv -> A_T
    float* in_iT   = w;  w += (size_t)SUB * T;   // dead after k_conv -> Z_T
    float* syn_sT  = w;  w += (size_t)NC * T;
    float* syn_nsT = w;  w += (size_t)SUB * T;
    float* PZ_T    = w;  w += (size_t)SUB * T;
    float* ke      = w;  w += SUB * TSYN;
    float* ki      = w;  w += SUB * TSYN;
    float* histk   = w;  w += NC * THIST;
    float* propk   = w;  w += SUB * THIST;
    int*   ae      = (int*)w;
    int*   ai      = ae + E;
    float* A_T     = in_eT;
    float* Z_T     = in_iT;

    int NB = (T + LSEG - 1) / LSEG;   // time-parallel blocks (157 at T=10000)
    int T4 = T >> 2;

    int nprep = E + I + SUB * 2 * TSYN + NC * THIST + SUB * THIST;
    hipLaunchKernelGGL(k_prep, dim3((nprep + 255) / 256), dim3(256), 0, stream,
                       C_syn_e, C_syn_i, W_ns_syn, Delta_ns_syn, W_ns_hist, W_ns_prop,
                       ae, ai, ke, ki, histk, propk, E, I);
    hipLaunchKernelGGL(k_insum, dim3(T), dim3(256), 0, stream,
                       S_e, S_i, ae, ai, W_s_syn, in_eT, in_iT, syn_sT, T, E, I);
    hipLaunchKernelGGL(k_conv, dim3((SUB * T4 + 255) / 256), dim3(256), 0, stream,
                       in_eT, in_iT, ke, ki, syn_nsT, T);
    hipLaunchKernelGGL(k_spk, dim3(NB), dim3(64), 0, stream,
                       syn_sT, Theta_s, spike_decay, C_den, W_s_prop, Zout, Xout, Z_T, T);
    hipLaunchKernelGGL(k_pz, dim3((SUB * T + 255) / 256), dim3(256), 0, stream,
                       Z_T, C_den, PZ_T, T);
    hipLaunchKernelGGL(k_A, dim3((SUB * T4 + 255) / 256), dim3(256), 0, stream,
                       syn_nsT, PZ_T, Z_T, histk, propk, Theta_ns, A_T, T);
    hipLaunchKernelGGL(k_y, dim3(NB), dim3(64), 0, stream,
                       A_T, C_den, W_ns_sub, V_o, Vout, Yout, T);
}

// Round 8
// 285.293 us; speedup vs baseline: 32.8492x; 1.0689x over previous
//
#include <hip/hip_runtime.h>
#include <math.h>

#define SUB 20       // sub_no
#define NC 19        // sub_no - 1
#define TSYN 200
#define THIST 50
#define BNUM 3
#define CHS 256      // serial-kernel LDS staging chunk (power of 2, mult of 4)
#define CHSP (CHS+4) // padded stride for float4-staged input rows
#define LSEG 40      // live segment length per block (mult of 4; NB=250 at T=10000)
#define WARMS 64     // spike warm-up steps (mult of 4): 0.4^k decay + exact resets
#define WARMY 48     // Y warm-up steps (mult of 4): contraction <=0.75/step

// ---------------------------------------------------------------------------
// k_prep: assignment indices from one-hot C_syn, plus the three alpha-basis
// kernels (syn with delta shift, hist, prop).
// ---------------------------------------------------------------------------
__global__ void k_prep(const float* __restrict__ C_syn_e, const float* __restrict__ C_syn_i,
                       const float* __restrict__ W_ns_syn, const float* __restrict__ Delta_ns_syn,
                       const float* __restrict__ W_ns_hist, const float* __restrict__ W_ns_prop,
                       int* __restrict__ ae, int* __restrict__ ai,
                       float* __restrict__ ke, float* __restrict__ ki,
                       float* __restrict__ histk, float* __restrict__ propk,
                       int E, int I)
{
    int idx = blockIdx.x * blockDim.x + threadIdx.x;
    if (idx < E) {
        int a = 0;
        for (int s = 0; s < SUB; ++s) if (C_syn_e[(size_t)s * E + idx] != 0.f) a = s;
        ae[idx] = a;
        return;
    }
    idx -= E;
    if (idx < I) {
        int a = 0;
        for (int s = 0; s < SUB; ++s) if (C_syn_i[(size_t)s * I + idx] != 0.f) a = s;
        ai[idx] = a;
        return;
    }
    idx -= I;
    if (idx < SUB * 2 * TSYN) {
        int j   = idx % TSYN;
        int rem = idx / TSYN;
        int c2  = rem & 1;
        int s   = rem >> 1;
        float delta = expf(Delta_ns_syn[s * 2 + c2]);
        float ts = fmaxf((float)j - delta, 0.f);
        float acc = 0.f;
        for (int b = 0; b < BNUM; ++b) {
            float tau = expf((float)b);
            float tt = ts / tau;
            acc += W_ns_syn[s * 6 + b * 2 + c2] * tt * expf(-tt);
        }
        if (c2 == 0) ke[s * TSYN + j] = acc; else ki[s * TSYN + j] = acc;
        return;
    }
    idx -= SUB * 2 * TSYN;
    if (idx < NC * THIST) {
        int j = idx % THIST, c = idx / THIST;
        float acc = 0.f;
        for (int b = 0; b < BNUM; ++b) {
            float tau = expf((float)b);
            float tt = (float)j / tau;
            acc += W_ns_hist[c * 3 + b] * tt * expf(-tt);
        }
        histk[c * THIST + j] = acc;
        return;
    }
    idx -= NC * THIST;
    if (idx < SUB * THIST) {
        int j = idx % THIST, s = idx / THIST;
        float acc = 0.f;
        for (int b = 0; b < BNUM; ++b) {
            float tau = expf((float)b);
            float tt = (float)j / tau;
            acc += W_ns_prop[s * 3 + b] * tt * expf(-tt);
        }
        propk[s * THIST + j] = acc;
    }
}

// ---------------------------------------------------------------------------
// k_insum: segment-sum per timestep (float4 spike loads) -> transposed
// [s][t] layouts + fused somatic synaptic drive syn_sT[c][t].
// ---------------------------------------------------------------------------
__global__ void k_insum(const float* __restrict__ Se, const float* __restrict__ Si,
                        const int* __restrict__ ae, const int* __restrict__ ai,
                        const float* __restrict__ W_s_syn,
                        float* __restrict__ in_eT, float* __restrict__ in_iT,
                        float* __restrict__ syn_sT,
                        int T, int E, int I)
{
    int t = blockIdx.x;
    __shared__ float le[SUB], li[SUB];
    if (threadIdx.x < SUB) { le[threadIdx.x] = 0.f; li[threadIdx.x] = 0.f; }
    __syncthreads();
    const float* Ser = Se + (size_t)t * E;
    const float* Sir = Si + (size_t)t * I;
    int E4 = E >> 2, I4 = I >> 2;
    for (int e4 = threadIdx.x; e4 < E4; e4 += blockDim.x) {
        float4 v = *(const float4*)(Ser + 4 * e4);
        if (v.x != 0.f) atomicAdd(&le[ae[4 * e4 + 0]], v.x);
        if (v.y != 0.f) atomicAdd(&le[ae[4 * e4 + 1]], v.y);
        if (v.z != 0.f) atomicAdd(&le[ae[4 * e4 + 2]], v.z);
        if (v.w != 0.f) atomicAdd(&le[ae[4 * e4 + 3]], v.w);
    }
    for (int e = 4 * E4 + threadIdx.x; e < E; e += blockDim.x) {
        float v = Ser[e];
        if (v != 0.f) atomicAdd(&le[ae[e]], v);
    }
    for (int i4 = threadIdx.x; i4 < I4; i4 += blockDim.x) {
        float4 v = *(const float4*)(Sir + 4 * i4);
        if (v.x != 0.f) atomicAdd(&li[ai[4 * i4 + 0]], v.x);
        if (v.y != 0.f) atomicAdd(&li[ai[4 * i4 + 1]], v.y);
        if (v.z != 0.f) atomicAdd(&li[ai[4 * i4 + 2]], v.z);
        if (v.w != 0.f) atomicAdd(&li[ai[4 * i4 + 3]], v.w);
    }
    for (int i = 4 * I4 + threadIdx.x; i < I; i += blockDim.x) {
        float v = Sir[i];
        if (v != 0.f) atomicAdd(&li[ai[i]], v);
    }
    __syncthreads();
    int s = threadIdx.x;
    if (s < SUB) {
        in_eT[(size_t)s * T + t] = le[s];
        in_iT[(size_t)s * T + t] = li[s];
        if (s >= 1)
            syn_sT[(size_t)(s - 1) * T + t] =
                le[s] * W_s_syn[s * 2 + 0] + li[s] * W_s_syn[s * 2 + 1];
    }
}

// ---------------------------------------------------------------------------
// k_conv: 200-tap causal conv, 4 outputs/thread via sliding-window registers.
// ---------------------------------------------------------------------------
__global__ void k_conv(const float* __restrict__ in_eT, const float* __restrict__ in_iT,
                       const float* __restrict__ ke, const float* __restrict__ ki,
                       float* __restrict__ syn_nsT, int T)
{
    int T4 = T >> 2;
    int idx = blockIdx.x * blockDim.x + threadIdx.x;
    if (idx >= SUB * T4) return;
    int s = idx / T4, t4 = idx - s * T4;
    int t = 4 * t4;
    const float* be = in_eT + (size_t)s * T;
    const float* bi = in_iT + (size_t)s * T;
    const float* kes = ke + s * TSYN;
    const float* kis = ki + s * TSYN;
    float ea = be[t + 3], eb = be[t + 2], ec = be[t + 1], ed = be[t];
    float ia = bi[t + 3], ib = bi[t + 2], ic = bi[t + 1], id = bi[t];
    float a0 = 0.f, a1 = 0.f, a2 = 0.f, a3 = 0.f;
    int jend = min(TSYN - 1, t + 3);
    for (int j = 0; j <= jend; ++j) {
        float kej = kes[j], kij = kis[j];
        a3 = fmaf(ea, kej, a3); a3 = fmaf(ia, kij, a3);
        a2 = fmaf(eb, kej, a2); a2 = fmaf(ib, kij, a2);
        a1 = fmaf(ec, kej, a1); a1 = fmaf(ic, kij, a1);
        a0 = fmaf(ed, kej, a0); a0 = fmaf(id, kij, a0);
        ea = eb; eb = ec; ec = ed;
        ia = ib; ib = ic; ic = id;
        int off = t - 1 - j;
        ed = (off >= 0) ? be[off] : 0.f;
        id = (off >= 0) ? bi[off] : 0.f;
    }
    *(float4*)(syn_nsT + (size_t)s * T + t) = make_float4(a0, a1, a2, a3);
}

// ---------------------------------------------------------------------------
// k_spk: spike recurrence, TIME-PARALLEL (250 blocks x 40-step live segment,
// 64-step speculative warm-up). Per-step math identical to R5-R7. Epilogue
// additionally computes PZ_T (k_pz fused: 19-term bit-test dot on the ballot
// masks already in LDS) and the transposed Z_T, all bulk-stored coalesced.
// ---------------------------------------------------------------------------
__global__ __launch_bounds__(64) void k_spk(const float* __restrict__ syn_sT,
                      const float* __restrict__ Theta_s, const float* __restrict__ spike_decay,
                      const float* __restrict__ C_den, const float* __restrict__ W_s_prop,
                      float* __restrict__ Zout, float* __restrict__ Xout,
                      float* __restrict__ Z_T, float* __restrict__ PZ_T, int T)
{
    __shared__ float S[NC * CHSP];      // staged syn input ([c][tl], float4 rows)
    __shared__ float SX[CHS * SUB];     // buffered x ([tl][c], stride 20)
    __shared__ unsigned ZM[CHS];        // buffered z ballot masks
    __shared__ float PZb[LSEG * SUB];   // fused-pz scratch ([tl][s])
    int lane = threadIdx.x;
    int c = lane;
    bool act = c < NC;
    int t0 = blockIdx.x * LSEG;
    if (t0 >= T) return;
    int t1 = min(t0 + LSEG, T);
    int tw = max(0, t0 - WARMS);

    float M[NC];
    #pragma unroll
    for (int j = 0; j < NC; ++j)
        M[j] = act ? C_den[(c + 1) * SUB + (j + 1)] * W_s_prop[j] : 0.f;
    float Cp[NC];                        // row for fused PZ: C_den[lane][c+1]
    #pragma unroll
    for (int j = 0; j < NC; ++j)
        Cp[j] = (lane < SUB) ? C_den[lane * SUB + (j + 1)] : 0.f;
    float theta = act ? Theta_s[c] : 0.f;
    float decay = act ? spike_decay[c] : 0.f;

    float x = 0.f;
    unsigned zlo = 0u;
    for (int tc = tw; tc < t1; tc += CHS) {
        int len = min(CHS, t1 - tc);     // multiple of 4
        __syncthreads();
        for (int r = lane; r < (NC * CHS) / 4; r += 64) {
            int e = r * 4;
            int cc = e >> 8;           // e / CHS
            int tl = e & (CHS - 1);    // e % CHS
            if (tl < len) {
                float4 v = *(const float4*)(syn_sT + (size_t)cc * T + tc + tl);
                *(float4*)(&S[cc * CHSP + tl]) = v;
            }
        }
        __syncthreads();
        float4 cur = act ? *(float4*)(&S[c * CHSP]) : make_float4(0.f, 0.f, 0.f, 0.f);
        for (int g = 0; g < len; g += 4) {
            float4 nxt = (act && g + 4 < len) ? *(float4*)(&S[c * CHSP + g + 4]) : cur;
            #pragma unroll
            for (int q = 0; q < 4; ++q) {
                float syn = (q == 0) ? cur.x : (q == 1) ? cur.y : (q == 2) ? cur.z : cur.w;
                float P = 0.f;
                #pragma unroll
                for (int j = 0; j < NC; ++j) {
                    float b = (float)((zlo >> j) & 1u);
                    P = fmaf(b, M[j], P);               // exact: b in {0,1}
                }
                float xin = fmaf(x, decay, syn);
                xin += P;
                xin += theta;
                bool zb = xin >= 0.f;
                zlo = (unsigned)__ballot(zb);
                x = zb ? 0.f : xin;
                int tl = g + q;
                if (act) SX[tl * SUB + c] = x;
                if (lane == NC) ZM[tl] = zlo;
            }
            cur = nxt;
        }
        __syncthreads();
        if (tc + len > t0) {
            int tls = max(0, t0 - tc);          // live range start within chunk
            int nl  = len - tls;                // live steps this chunk (<= LSEG)
            // fused k_pz: PZ[s][u] from ballot masks (parallel across lanes)
            if (lane < SUB) {
                for (int tl = 0; tl < nl; ++tl) {
                    unsigned m = ZM[tls + tl];
                    float acc = 0.f;
                    #pragma unroll
                    for (int j = 0; j < NC; ++j)
                        acc = fmaf((float)((m >> j) & 1u), Cp[j], acc);
                    PZb[tl * SUB + lane] = acc;
                }
            }
            __syncthreads();
            for (int r = lane; r < nl * NC; r += 64) {
                int tl = r / NC;
                int cc = r - tl * NC;
                size_t o = (size_t)(t0 + tl) * NC + cc;  // note: t0 valid only when
                Zout[o] = (float)((ZM[tls + tl] >> cc) & 1u);
                Xout[o] = SX[(tls + tl) * SUB + cc];
            }
            for (int r = lane; r < nl * NC; r += 64) {
                int cc = r / nl;
                int tl = r - cc * nl;
                Z_T[(size_t)cc * T + (tc + tls + tl)] = (float)((ZM[tls + tl] >> cc) & 1u);
            }
            for (int r = lane; r < nl * SUB; r += 64) {
                int cc = r / nl;
                int tl = r - cc * nl;
                PZ_T[(size_t)cc * T + (tc + tls + tl)] = PZb[tl * SUB + cc];
            }
        }
    }
}

// ---------------------------------------------------------------------------
// k_A: A_T[s][t] = syn_ns + Theta_ns + f_prop (+ f_hist for s>=1),
// 4 outputs/thread via sliding-window registers over PZ_T / Z_T.
// ---------------------------------------------------------------------------
__global__ void k_A(const float* __restrict__ syn_nsT, const float* __restrict__ PZ_T,
                    const float* __restrict__ Z_T, const float* __restrict__ histk,
                    const float* __restrict__ propk, const float* __restrict__ Theta_ns,
                    float* __restrict__ A_T, int T)
{
    int T4 = T >> 2;
    int idx = blockIdx.x * blockDim.x + threadIdx.x;
    if (idx >= SUB * T4) return;
    int s = idx / T4, t4 = idx - s * T4;
    int t = 4 * t4;
    float4 sy = *(const float4*)(syn_nsT + (size_t)s * T + t);
    float th = Theta_ns[s];
    float u0 = sy.x + th, u1 = sy.y + th, u2 = sy.z + th, u3 = sy.w + th;
    {
        const float* bp = PZ_T + (size_t)s * T;
        const float* pk = propk + s * THIST;
        float pa = bp[t + 2], pb = bp[t + 1], pc = bp[t];
        float pd = (t - 1 >= 0) ? bp[t - 1] : 0.f;
        int jend = min(THIST - 1, t + 2);
        for (int j = 0; j <= jend; ++j) {
            float k = pk[j];
            u3 = fmaf(pa, k, u3); u2 = fmaf(pb, k, u2);
            u1 = fmaf(pc, k, u1); u0 = fmaf(pd, k, u0);
            pa = pb; pb = pc; pc = pd;
            int off = t - 2 - j;
            pd = (off >= 0) ? bp[off] : 0.f;
        }
    }
    if (s >= 1) {
        const float* bz = Z_T + (size_t)(s - 1) * T;
        const float* hk = histk + (s - 1) * THIST;
        float pa = bz[t + 2], pb = bz[t + 1], pc = bz[t];
        float pd = (t - 1 >= 0) ? bz[t - 1] : 0.f;
        int jend = min(THIST - 1, t + 2);
        for (int j = 0; j <= jend; ++j) {
            float k = hk[j];
            u3 = fmaf(pa, k, u3); u2 = fmaf(pb, k, u2);
            u1 = fmaf(pc, k, u1); u0 = fmaf(pd, k, u0);
            pa = pb; pb = pc; pc = pd;
            int off = t - 2 - j;
            pd = (off >= 0) ? bz[off] : 0.f;
        }
    }
    *(float4*)(A_T + (size_t)s * T + t) = make_float4(u0, u1, u2, u3);
}

// ---------------------------------------------------------------------------
// k_y: Y recurrence, TIME-PARALLEL (250 blocks x 40-step live segment,
// 48-step warm-up; contraction <=0.75/step => warm-up error ~1e-6, invisible
// vs the 2e-2/bf16 floor). Per-step math identical to R5-R7.
// ---------------------------------------------------------------------------
__global__ __launch_bounds__(64) void k_y(const float* __restrict__ A_T,
                    const float* __restrict__ C_den, const float* __restrict__ W_ns_sub,
                    const float* __restrict__ V_o,
                    float* __restrict__ Vout, float* __restrict__ Yout, int T)
{
    __shared__ float S[SUB * CHSP];
    __shared__ float SY[CHS * SUB];
    __shared__ __align__(16) float ybc[64];
    int lane = threadIdx.x;
    int s = lane;
    bool act = s < SUB;
    int t0 = blockIdx.x * LSEG;
    if (t0 >= T) return;
    int t1 = min(t0 + LSEG, T);
    int tw = max(0, t0 - WARMY);

    float Crow[SUB];
    #pragma unroll
    for (int j = 0; j < SUB; ++j)
        Crow[j] = act ? C_den[s * SUB + j] : 0.f;
    float wsub = act ? W_ns_sub[s] : 0.f;
    float vo = V_o[0];

    ybc[lane] = 0.f;
    __syncthreads();

    for (int tc = tw; tc < t1; tc += CHS) {
        int len = min(CHS, t1 - tc);     // multiple of 4
        __syncthreads();
        for (int r = lane; r < (SUB * CHS) / 4; r += 64) {
            int e = r * 4;
            int cc = e >> 8;
            int tl = e & (CHS - 1);
            if (tl < len) {
                float4 v = *(const float4*)(A_T + (size_t)cc * T + tc + tl);
                *(float4*)(&S[cc * CHSP + tl]) = v;
            }
        }
        __syncthreads();
        float4 cur = act ? *(float4*)(&S[s * CHSP]) : make_float4(0.f, 0.f, 0.f, 0.f);
        for (int g = 0; g < len; g += 4) {
            float4 nxt = (act && g + 4 < len) ? *(float4*)(&S[s * CHSP + g + 4]) : cur;
            #pragma unroll
            for (int q = 0; q < 4; ++q) {
                float a = (q == 0) ? cur.x : (q == 1) ? cur.y : (q == 2) ? cur.z : cur.w;
                __builtin_amdgcn_wave_barrier();
                float4 Y0 = *(const float4*)(&ybc[0]);
                float4 Y1 = *(const float4*)(&ybc[4]);
                float4 Y2 = *(const float4*)(&ybc[8]);
                float4 Y3 = *(const float4*)(&ybc[12]);
                float4 Y4 = *(const float4*)(&ybc[16]);
                float u0 = a, u1 = 0.f, u2 = 0.f, u3 = 0.f;
                u0 += Crow[0]  * Y0.x;  u1 += Crow[1]  * Y0.y;
                u2 += Crow[2]  * Y0.z;  u3 += Crow[3]  * Y0.w;
                u0 += Crow[4]  * Y1.x;  u1 += Crow[5]  * Y1.y;
                u2 += Crow[6]  * Y1.z;  u3 += Crow[7]  * Y1.w;
                u0 += Crow[8]  * Y2.x;  u1 += Crow[9]  * Y2.y;
                u2 += Crow[10] * Y2.z;  u3 += Crow[11] * Y2.w;
                u0 += Crow[12] * Y3.x;  u1 += Crow[13] * Y3.y;
                u2 += Crow[14] * Y3.z;  u3 += Crow[15] * Y3.w;
                u0 += Crow[16] * Y4.x;  u1 += Crow[17] * Y4.y;
                u2 += Crow[18] * Y4.z;  u3 += Crow[19] * Y4.w;
                float u = (u0 + u1) + (u2 + u3);
                float y = wsub / (1.f + __expf(-u));   // lanes>=20 -> 0
                __builtin_amdgcn_wave_barrier();
                ybc[lane] = y;
                int tl = g + q;
                if (act) SY[tl * SUB + s] = y;
            }
            cur = nxt;
        }
        __syncthreads();
        if (tc + len > t0) {
            for (int r = lane; r < len * SUB; r += 64) {
                int tl = r / SUB;
                int cc = r - tl * SUB;
                int tg = tc + tl;
                if (tg >= t0) {
                    float y = SY[r];
                    if (cc == 0) Vout[tg] = y + vo;
                    else         Yout[(size_t)tg * NC + (cc - 1)] = y;
                }
            }
        }
    }
}

// ---------------------------------------------------------------------------
extern "C" void kernel_launch(void* const* d_in, const int* in_sizes, int n_in,
                              void* d_out, int out_size, void* d_ws, size_t ws_size,
                              hipStream_t stream)
{
    const float* S_e          = (const float*)d_in[0];
    const float* S_i          = (const float*)d_in[1];
    const float* C_den        = (const float*)d_in[2];
    const float* C_syn_e      = (const float*)d_in[3];
    const float* C_syn_i      = (const float*)d_in[4];
    const float* W_s_syn      = (const float*)d_in[5];
    const float* W_ns_syn     = (const float*)d_in[6];
    const float* Delta_ns_syn = (const float*)d_in[7];
    const float* W_ns_sub     = (const float*)d_in[8];
    const float* V_o          = (const float*)d_in[9];
    const float* Theta_s      = (const float*)d_in[10];
    const float* Theta_ns     = (const float*)d_in[11];
    const float* W_ns_hist    = (const float*)d_in[12];
    const float* W_s_prop     = (const float*)d_in[13];
    const float* W_ns_prop    = (const float*)d_in[14];
    const float* spike_decay  = (const float*)d_in[15];

    int E = in_sizes[3] / SUB;
    int I = in_sizes[4] / SUB;
    int T = in_sizes[0] / E;

    float* out  = (float*)d_out;
    float* Vout = out;                           // [T]
    float* Yout = out + (size_t)T;               // [T, 19]
    float* Zout = out + (size_t)T * (1 + NC);    // [T, 19]
    float* Xout = out + (size_t)T * (1 + 2*NC);  // [T, 19]

    float* w       = (float*)d_ws;
    float* in_eT   = w;  w += (size_t)SUB * T;   // dead after k_conv -> A_T
    float* in_iT   = w;  w += (size_t)SUB * T;   // dead after k_conv -> Z_T
    float* syn_sT  = w;  w += (size_t)NC * T;
    float* syn_nsT = w;  w += (size_t)SUB * T;
    float* PZ_T    = w;  w += (size_t)SUB * T;
    float* ke      = w;  w += SUB * TSYN;
    float* ki      = w;  w += SUB * TSYN;
    float* histk   = w;  w += NC * THIST;
    float* propk   = w;  w += SUB * THIST;
    int*   ae      = (int*)w;
    int*   ai      = ae + E;
    float* A_T     = in_eT;
    float* Z_T     = in_iT;

    int NB = (T + LSEG - 1) / LSEG;   // time-parallel blocks (250 at T=10000)
    int T4 = T >> 2;

    int nprep = E + I + SUB * 2 * TSYN + NC * THIST + SUB * THIST;
    hipLaunchKernelGGL(k_prep, dim3((nprep + 255) / 256), dim3(256), 0, stream,
                       C_syn_e, C_syn_i, W_ns_syn, Delta_ns_syn, W_ns_hist, W_ns_prop,
                       ae, ai, ke, ki, histk, propk, E, I);
    hipLaunchKernelGGL(k_insum, dim3(T), dim3(256), 0, stream,
                       S_e, S_i, ae, ai, W_s_syn, in_eT, in_iT, syn_sT, T, E, I);
    hipLaunchKernelGGL(k_conv, dim3((SUB * T4 + 255) / 256), dim3(256), 0, stream,
                       in_eT, in_iT, ke, ki, syn_nsT, T);
    hipLaunchKernelGGL(k_spk, dim3(NB), dim3(64), 0, stream,
                       syn_sT, Theta_s, spike_decay, C_den, W_s_prop,
                       Zout, Xout, Z_T, PZ_T, T);
    hipLaunchKernelGGL(k_A, dim3((SUB * T4 + 255) / 256), dim3(256), 0, stream,
                       syn_nsT, PZ_T, Z_T, histk, propk, Theta_ns, A_T, T);
    hipLaunchKernelGGL(k_y, dim3(NB), dim3(64), 0, stream,
                       A_T, C_den, W_ns_sub, V_o, Vout, Yout, T);
}

// Round 9
// 256.732 us; speedup vs baseline: 36.5036x; 1.1113x over previous
//
#include <hip/hip_runtime.h>
#include <math.h>

#define SUB 20       // sub_no
#define NC 19        // sub_no - 1
#define TSYN 200
#define THIST 50
#define BNUM 3
#define CHS 128      // serial-kernel LDS staging chunk (power of 2, >= LSEG+WARM)
#define CHSP (CHS+4) // padded stride for float4-staged input rows
#define LSEG 40      // live segment length per block (mult of 4; NB=250 at T=10000)
#define WARMS 48     // spike warm-up steps (mult of 4): 0.4^k decay + exact resets
#define WARMY 48     // Y warm-up steps (mult of 4): contraction <=0.75/step

// ---------------------------------------------------------------------------
// k_prep: assignment indices from one-hot C_syn, plus the three alpha-basis
// kernels (syn with delta shift, hist, prop).
// ---------------------------------------------------------------------------
__global__ void k_prep(const float* __restrict__ C_syn_e, const float* __restrict__ C_syn_i,
                       const float* __restrict__ W_ns_syn, const float* __restrict__ Delta_ns_syn,
                       const float* __restrict__ W_ns_hist, const float* __restrict__ W_ns_prop,
                       int* __restrict__ ae, int* __restrict__ ai,
                       float* __restrict__ ke, float* __restrict__ ki,
                       float* __restrict__ histk, float* __restrict__ propk,
                       int E, int I)
{
    int idx = blockIdx.x * blockDim.x + threadIdx.x;
    if (idx < E) {
        int a = 0;
        for (int s = 0; s < SUB; ++s) if (C_syn_e[(size_t)s * E + idx] != 0.f) a = s;
        ae[idx] = a;
        return;
    }
    idx -= E;
    if (idx < I) {
        int a = 0;
        for (int s = 0; s < SUB; ++s) if (C_syn_i[(size_t)s * I + idx] != 0.f) a = s;
        ai[idx] = a;
        return;
    }
    idx -= I;
    if (idx < SUB * 2 * TSYN) {
        int j   = idx % TSYN;
        int rem = idx / TSYN;
        int c2  = rem & 1;
        int s   = rem >> 1;
        float delta = expf(Delta_ns_syn[s * 2 + c2]);
        float ts = fmaxf((float)j - delta, 0.f);
        float acc = 0.f;
        for (int b = 0; b < BNUM; ++b) {
            float tau = expf((float)b);
            float tt = ts / tau;
            acc += W_ns_syn[s * 6 + b * 2 + c2] * tt * expf(-tt);
        }
        if (c2 == 0) ke[s * TSYN + j] = acc; else ki[s * TSYN + j] = acc;
        return;
    }
    idx -= SUB * 2 * TSYN;
    if (idx < NC * THIST) {
        int j = idx % THIST, c = idx / THIST;
        float acc = 0.f;
        for (int b = 0; b < BNUM; ++b) {
            float tau = expf((float)b);
            float tt = (float)j / tau;
            acc += W_ns_hist[c * 3 + b] * tt * expf(-tt);
        }
        histk[c * THIST + j] = acc;
        return;
    }
    idx -= NC * THIST;
    if (idx < SUB * THIST) {
        int j = idx % THIST, s = idx / THIST;
        float acc = 0.f;
        for (int b = 0; b < BNUM; ++b) {
            float tau = expf((float)b);
            float tt = (float)j / tau;
            acc += W_ns_prop[s * 3 + b] * tt * expf(-tt);
        }
        propk[s * THIST + j] = acc;
    }
}

// ---------------------------------------------------------------------------
// k_insum: segment-sum per timestep (float4 spike loads) -> transposed
// [s][t] layouts + fused somatic synaptic drive syn_sT[c][t].
// ---------------------------------------------------------------------------
__global__ void k_insum(const float* __restrict__ Se, const float* __restrict__ Si,
                        const int* __restrict__ ae, const int* __restrict__ ai,
                        const float* __restrict__ W_s_syn,
                        float* __restrict__ in_eT, float* __restrict__ in_iT,
                        float* __restrict__ syn_sT,
                        int T, int E, int I)
{
    int t = blockIdx.x;
    __shared__ float le[SUB], li[SUB];
    if (threadIdx.x < SUB) { le[threadIdx.x] = 0.f; li[threadIdx.x] = 0.f; }
    __syncthreads();
    const float* Ser = Se + (size_t)t * E;
    const float* Sir = Si + (size_t)t * I;
    int E4 = E >> 2, I4 = I >> 2;
    for (int e4 = threadIdx.x; e4 < E4; e4 += blockDim.x) {
        float4 v = *(const float4*)(Ser + 4 * e4);
        if (v.x != 0.f) atomicAdd(&le[ae[4 * e4 + 0]], v.x);
        if (v.y != 0.f) atomicAdd(&le[ae[4 * e4 + 1]], v.y);
        if (v.z != 0.f) atomicAdd(&le[ae[4 * e4 + 2]], v.z);
        if (v.w != 0.f) atomicAdd(&le[ae[4 * e4 + 3]], v.w);
    }
    for (int e = 4 * E4 + threadIdx.x; e < E; e += blockDim.x) {
        float v = Ser[e];
        if (v != 0.f) atomicAdd(&le[ae[e]], v);
    }
    for (int i4 = threadIdx.x; i4 < I4; i4 += blockDim.x) {
        float4 v = *(const float4*)(Sir + 4 * i4);
        if (v.x != 0.f) atomicAdd(&li[ai[4 * i4 + 0]], v.x);
        if (v.y != 0.f) atomicAdd(&li[ai[4 * i4 + 1]], v.y);
        if (v.z != 0.f) atomicAdd(&li[ai[4 * i4 + 2]], v.z);
        if (v.w != 0.f) atomicAdd(&li[ai[4 * i4 + 3]], v.w);
    }
    for (int i = 4 * I4 + threadIdx.x; i < I; i += blockDim.x) {
        float v = Sir[i];
        if (v != 0.f) atomicAdd(&li[ai[i]], v);
    }
    __syncthreads();
    int s = threadIdx.x;
    if (s < SUB) {
        in_eT[(size_t)s * T + t] = le[s];
        in_iT[(size_t)s * T + t] = li[s];
        if (s >= 1)
            syn_sT[(size_t)(s - 1) * T + t] =
                le[s] * W_s_syn[s * 2 + 0] + li[s] * W_s_syn[s * 2 + 1];
    }
}

// ---------------------------------------------------------------------------
// k_spkconv: FUSED dispatch. Blocks [0,NB): time-parallel spike recurrence
// (identical math to R5-R8; 40-step live + 48-step speculative warm-up;
// epilogue computes Z/X outputs, transposed Z_T and fused PZ_T). Blocks
// [NB,...): the 200-tap causal conv (64-thread indexing) — independent work
// that hides under the latency-bound spike blocks, saving a dispatch.
// ---------------------------------------------------------------------------
__global__ __launch_bounds__(64) void k_spkconv(
                      const float* __restrict__ syn_sT,
                      const float* __restrict__ Theta_s, const float* __restrict__ spike_decay,
                      const float* __restrict__ C_den, const float* __restrict__ W_s_prop,
                      float* __restrict__ Zout, float* __restrict__ Xout,
                      float* __restrict__ Z_T, float* __restrict__ PZ_T,
                      const float* __restrict__ in_eT, const float* __restrict__ in_iT,
                      const float* __restrict__ ke, const float* __restrict__ ki,
                      float* __restrict__ syn_nsT,
                      int T, int NB)
{
    __shared__ float S[NC * CHSP];      // staged syn input ([c][tl], float4 rows)
    __shared__ float SX[CHS * SUB];     // buffered x ([tl][c], stride 20)
    __shared__ unsigned ZM[CHS];        // buffered z ballot masks
    __shared__ float PZb[LSEG * SUB];   // fused-pz scratch ([tl][s])
    int lane = threadIdx.x;

    if (blockIdx.x >= NB) {
        // ---- conv part: 4 outputs/thread, sliding-window registers ----
        int T4 = T >> 2;
        int idx = (blockIdx.x - NB) * 64 + lane;
        if (idx >= SUB * T4) return;
        int s = idx / T4, t4 = idx - s * T4;
        int t = 4 * t4;
        const float* be = in_eT + (size_t)s * T;
        const float* bi = in_iT + (size_t)s * T;
        const float* kes = ke + s * TSYN;
        const float* kis = ki + s * TSYN;
        float ea = be[t + 3], eb = be[t + 2], ec = be[t + 1], ed = be[t];
        float ia = bi[t + 3], ib = bi[t + 2], ic = bi[t + 1], id = bi[t];
        float a0 = 0.f, a1 = 0.f, a2 = 0.f, a3 = 0.f;
        int jend = min(TSYN - 1, t + 3);
        for (int j = 0; j <= jend; ++j) {
            float kej = kes[j], kij = kis[j];
            a3 = fmaf(ea, kej, a3); a3 = fmaf(ia, kij, a3);
            a2 = fmaf(eb, kej, a2); a2 = fmaf(ib, kij, a2);
            a1 = fmaf(ec, kej, a1); a1 = fmaf(ic, kij, a1);
            a0 = fmaf(ed, kej, a0); a0 = fmaf(id, kij, a0);
            ea = eb; eb = ec; ec = ed;
            ia = ib; ib = ic; ic = id;
            int off = t - 1 - j;
            ed = (off >= 0) ? be[off] : 0.f;
            id = (off >= 0) ? bi[off] : 0.f;
        }
        *(float4*)(syn_nsT + (size_t)s * T + t) = make_float4(a0, a1, a2, a3);
        return;
    }

    // ---- spike part ----
    int c = lane;
    bool act = c < NC;
    int t0 = blockIdx.x * LSEG;
    if (t0 >= T) return;
    int t1 = min(t0 + LSEG, T);
    int tw = max(0, t0 - WARMS);

    float M[NC];
    #pragma unroll
    for (int j = 0; j < NC; ++j)
        M[j] = act ? C_den[(c + 1) * SUB + (j + 1)] * W_s_prop[j] : 0.f;
    float Cp[NC];                        // row for fused PZ: C_den[lane][c+1]
    #pragma unroll
    for (int j = 0; j < NC; ++j)
        Cp[j] = (lane < SUB) ? C_den[lane * SUB + (j + 1)] : 0.f;
    float theta = act ? Theta_s[c] : 0.f;
    float decay = act ? spike_decay[c] : 0.f;

    float x = 0.f;
    unsigned zlo = 0u;
    for (int tc = tw; tc < t1; tc += CHS) {
        int len = min(CHS, t1 - tc);     // multiple of 4
        __syncthreads();
        for (int r = lane; r < (NC * CHS) / 4; r += 64) {
            int e = r * 4;
            int cc = e >> 7;           // e / CHS
            int tl = e & (CHS - 1);    // e % CHS
            if (tl < len) {
                float4 v = *(const float4*)(syn_sT + (size_t)cc * T + tc + tl);
                *(float4*)(&S[cc * CHSP + tl]) = v;
            }
        }
        __syncthreads();
        float4 cur = act ? *(float4*)(&S[c * CHSP]) : make_float4(0.f, 0.f, 0.f, 0.f);
        for (int g = 0; g < len; g += 4) {
            float4 nxt = (act && g + 4 < len) ? *(float4*)(&S[c * CHSP + g + 4]) : cur;
            #pragma unroll
            for (int q = 0; q < 4; ++q) {
                float syn = (q == 0) ? cur.x : (q == 1) ? cur.y : (q == 2) ? cur.z : cur.w;
                float P = 0.f;
                #pragma unroll
                for (int j = 0; j < NC; ++j) {
                    float b = (float)((zlo >> j) & 1u);
                    P = fmaf(b, M[j], P);               // exact: b in {0,1}
                }
                float xin = fmaf(x, decay, syn);
                xin += P;
                xin += theta;
                bool zb = xin >= 0.f;
                zlo = (unsigned)__ballot(zb);
                x = zb ? 0.f : xin;
                int tl = g + q;
                if (act) SX[tl * SUB + c] = x;
                if (lane == NC) ZM[tl] = zlo;
            }
            cur = nxt;
        }
        __syncthreads();
        if (tc + len > t0) {
            int tls = max(0, t0 - tc);          // live range start within chunk
            int nl  = len - tls;                // live steps this chunk (<= LSEG)
            // fused k_pz: PZ[s][u] from ballot masks (parallel across lanes)
            if (lane < SUB) {
                for (int tl = 0; tl < nl; ++tl) {
                    unsigned m = ZM[tls + tl];
                    float acc = 0.f;
                    #pragma unroll
                    for (int j = 0; j < NC; ++j)
                        acc = fmaf((float)((m >> j) & 1u), Cp[j], acc);
                    PZb[tl * SUB + lane] = acc;
                }
            }
            __syncthreads();
            for (int r = lane; r < nl * NC; r += 64) {
                int tl = r / NC;
                int cc = r - tl * NC;
                size_t o = (size_t)(t0 + tl) * NC + cc;
                Zout[o] = (float)((ZM[tls + tl] >> cc) & 1u);
                Xout[o] = SX[(tls + tl) * SUB + cc];
            }
            for (int r = lane; r < nl * NC; r += 64) {
                int cc = r / nl;
                int tl = r - cc * nl;
                Z_T[(size_t)cc * T + (tc + tls + tl)] = (float)((ZM[tls + tl] >> cc) & 1u);
            }
            for (int r = lane; r < nl * SUB; r += 64) {
                int cc = r / nl;
                int tl = r - cc * nl;
                PZ_T[(size_t)cc * T + (tc + tls + tl)] = PZb[tl * SUB + cc];
            }
        }
    }
}

// ---------------------------------------------------------------------------
// k_A: A_T[s][t] = syn_ns + Theta_ns + f_prop (+ f_hist for s>=1),
// 4 outputs/thread via sliding-window registers over PZ_T / Z_T.
// ---------------------------------------------------------------------------
__global__ void k_A(const float* __restrict__ syn_nsT, const float* __restrict__ PZ_T,
                    const float* __restrict__ Z_T, const float* __restrict__ histk,
                    const float* __restrict__ propk, const float* __restrict__ Theta_ns,
                    float* __restrict__ A_T, int T)
{
    int T4 = T >> 2;
    int idx = blockIdx.x * blockDim.x + threadIdx.x;
    if (idx >= SUB * T4) return;
    int s = idx / T4, t4 = idx - s * T4;
    int t = 4 * t4;
    float4 sy = *(const float4*)(syn_nsT + (size_t)s * T + t);
    float th = Theta_ns[s];
    float u0 = sy.x + th, u1 = sy.y + th, u2 = sy.z + th, u3 = sy.w + th;
    {
        const float* bp = PZ_T + (size_t)s * T;
        const float* pk = propk + s * THIST;
        float pa = bp[t + 2], pb = bp[t + 1], pc = bp[t];
        float pd = (t - 1 >= 0) ? bp[t - 1] : 0.f;
        int jend = min(THIST - 1, t + 2);
        for (int j = 0; j <= jend; ++j) {
            float k = pk[j];
            u3 = fmaf(pa, k, u3); u2 = fmaf(pb, k, u2);
            u1 = fmaf(pc, k, u1); u0 = fmaf(pd, k, u0);
            pa = pb; pb = pc; pc = pd;
            int off = t - 2 - j;
            pd = (off >= 0) ? bp[off] : 0.f;
        }
    }
    if (s >= 1) {
        const float* bz = Z_T + (size_t)(s - 1) * T;
        const float* hk = histk + (s - 1) * THIST;
        float pa = bz[t + 2], pb = bz[t + 1], pc = bz[t];
        float pd = (t - 1 >= 0) ? bz[t - 1] : 0.f;
        int jend = min(THIST - 1, t + 2);
        for (int j = 0; j <= jend; ++j) {
            float k = hk[j];
            u3 = fmaf(pa, k, u3); u2 = fmaf(pb, k, u2);
            u1 = fmaf(pc, k, u1); u0 = fmaf(pd, k, u0);
            pa = pb; pb = pc; pc = pd;
            int off = t - 2 - j;
            pd = (off >= 0) ? bz[off] : 0.f;
        }
    }
    *(float4*)(A_T + (size_t)s * T + t) = make_float4(u0, u1, u2, u3);
}

// ---------------------------------------------------------------------------
// k_y: Y recurrence, TIME-PARALLEL (250 blocks x 40-step live segment,
// 48-step warm-up; contraction <=0.75/step => warm-up error ~1e-6, invisible
// vs the 2e-2/bf16 floor). Per-step math identical to R5-R8.
// ---------------------------------------------------------------------------
__global__ __launch_bounds__(64) void k_y(const float* __restrict__ A_T,
                    const float* __restrict__ C_den, const float* __restrict__ W_ns_sub,
                    const float* __restrict__ V_o,
                    float* __restrict__ Vout, float* __restrict__ Yout, int T)
{
    __shared__ float S[SUB * CHSP];
    __shared__ float SY[CHS * SUB];
    __shared__ __align__(16) float ybc[64];
    int lane = threadIdx.x;
    int s = lane;
    bool act = s < SUB;
    int t0 = blockIdx.x * LSEG;
    if (t0 >= T) return;
    int t1 = min(t0 + LSEG, T);
    int tw = max(0, t0 - WARMY);

    float Crow[SUB];
    #pragma unroll
    for (int j = 0; j < SUB; ++j)
        Crow[j] = act ? C_den[s * SUB + j] : 0.f;
    float wsub = act ? W_ns_sub[s] : 0.f;
    float vo = V_o[0];

    ybc[lane] = 0.f;
    __syncthreads();

    for (int tc = tw; tc < t1; tc += CHS) {
        int len = min(CHS, t1 - tc);     // multiple of 4
        __syncthreads();
        for (int r = lane; r < (SUB * CHS) / 4; r += 64) {
            int e = r * 4;
            int cc = e >> 7;
            int tl = e & (CHS - 1);
            if (tl < len) {
                float4 v = *(const float4*)(A_T + (size_t)cc * T + tc + tl);
                *(float4*)(&S[cc * CHSP + tl]) = v;
            }
        }
        __syncthreads();
        float4 cur = act ? *(float4*)(&S[s * CHSP]) : make_float4(0.f, 0.f, 0.f, 0.f);
        for (int g = 0; g < len; g += 4) {
            float4 nxt = (act && g + 4 < len) ? *(float4*)(&S[s * CHSP + g + 4]) : cur;
            #pragma unroll
            for (int q = 0; q < 4; ++q) {
                float a = (q == 0) ? cur.x : (q == 1) ? cur.y : (q == 2) ? cur.z : cur.w;
                __builtin_amdgcn_wave_barrier();
                float4 Y0 = *(const float4*)(&ybc[0]);
                float4 Y1 = *(const float4*)(&ybc[4]);
                float4 Y2 = *(const float4*)(&ybc[8]);
                float4 Y3 = *(const float4*)(&ybc[12]);
                float4 Y4 = *(const float4*)(&ybc[16]);
                float u0 = a, u1 = 0.f, u2 = 0.f, u3 = 0.f;
                u0 += Crow[0]  * Y0.x;  u1 += Crow[1]  * Y0.y;
                u2 += Crow[2]  * Y0.z;  u3 += Crow[3]  * Y0.w;
                u0 += Crow[4]  * Y1.x;  u1 += Crow[5]  * Y1.y;
                u2 += Crow[6]  * Y1.z;  u3 += Crow[7]  * Y1.w;
                u0 += Crow[8]  * Y2.x;  u1 += Crow[9]  * Y2.y;
                u2 += Crow[10] * Y2.z;  u3 += Crow[11] * Y2.w;
                u0 += Crow[12] * Y3.x;  u1 += Crow[13] * Y3.y;
                u2 += Crow[14] * Y3.z;  u3 += Crow[15] * Y3.w;
                u0 += Crow[16] * Y4.x;  u1 += Crow[17] * Y4.y;
                u2 += Crow[18] * Y4.z;  u3 += Crow[19] * Y4.w;
                float u = (u0 + u1) + (u2 + u3);
                float y = wsub / (1.f + __expf(-u));   // lanes>=20 -> 0
                __builtin_amdgcn_wave_barrier();
                ybc[lane] = y;
                int tl = g + q;
                if (act) SY[tl * SUB + s] = y;
            }
            cur = nxt;
        }
        __syncthreads();
        if (tc + len > t0) {
            for (int r = lane; r < len * SUB; r += 64) {
                int tl = r / SUB;
                int cc = r - tl * SUB;
                int tg = tc + tl;
                if (tg >= t0) {
                    float y = SY[r];
                    if (cc == 0) Vout[tg] = y + vo;
                    else         Yout[(size_t)tg * NC + (cc - 1)] = y;
                }
            }
        }
    }
}

// ---------------------------------------------------------------------------
extern "C" void kernel_launch(void* const* d_in, const int* in_sizes, int n_in,
                              void* d_out, int out_size, void* d_ws, size_t ws_size,
                              hipStream_t stream)
{
    const float* S_e          = (const float*)d_in[0];
    const float* S_i          = (const float*)d_in[1];
    const float* C_den        = (const float*)d_in[2];
    const float* C_syn_e      = (const float*)d_in[3];
    const float* C_syn_i      = (const float*)d_in[4];
    const float* W_s_syn      = (const float*)d_in[5];
    const float* W_ns_syn     = (const float*)d_in[6];
    const float* Delta_ns_syn = (const float*)d_in[7];
    const float* W_ns_sub     = (const float*)d_in[8];
    const float* V_o          = (const float*)d_in[9];
    const float* Theta_s      = (const float*)d_in[10];
    const float* Theta_ns     = (const float*)d_in[11];
    const float* W_ns_hist    = (const float*)d_in[12];
    const float* W_s_prop     = (const float*)d_in[13];
    const float* W_ns_prop    = (const float*)d_in[14];
    const float* spike_decay  = (const float*)d_in[15];

    int E = in_sizes[3] / SUB;
    int I = in_sizes[4] / SUB;
    int T = in_sizes[0] / E;

    float* out  = (float*)d_out;
    float* Vout = out;                           // [T]
    float* Yout = out + (size_t)T;               // [T, 19]
    float* Zout = out + (size_t)T * (1 + NC);    // [T, 19]
    float* Xout = out + (size_t)T * (1 + 2*NC);  // [T, 19]

    float* w       = (float*)d_ws;
    float* in_eT   = w;  w += (size_t)SUB * T;   // dead after k_spkconv -> A_T
    float* in_iT   = w;  w += (size_t)SUB * T;
    float* syn_sT  = w;  w += (size_t)NC * T;
    float* syn_nsT = w;  w += (size_t)SUB * T;
    float* PZ_T    = w;  w += (size_t)SUB * T;
    float* Z_T     = w;  w += (size_t)SUB * T;
    float* ke      = w;  w += SUB * TSYN;
    float* ki      = w;  w += SUB * TSYN;
    float* histk   = w;  w += NC * THIST;
    float* propk   = w;  w += SUB * THIST;
    int*   ae      = (int*)w;
    int*   ai      = ae + E;
    float* A_T     = in_eT;   // in_eT dead once conv (inside k_spkconv) done

    int NB = (T + LSEG - 1) / LSEG;   // time-parallel blocks (250 at T=10000)
    int T4 = T >> 2;
    int NCONV = (SUB * T4 + 63) / 64; // conv blocks appended to spk dispatch

    int nprep = E + I + SUB * 2 * TSYN + NC * THIST + SUB * THIST;
    hipLaunchKernelGGL(k_prep, dim3((nprep + 255) / 256), dim3(256), 0, stream,
                       C_syn_e, C_syn_i, W_ns_syn, Delta_ns_syn, W_ns_hist, W_ns_prop,
                       ae, ai, ke, ki, histk, propk, E, I);
    hipLaunchKernelGGL(k_insum, dim3(T), dim3(256), 0, stream,
                       S_e, S_i, ae, ai, W_s_syn, in_eT, in_iT, syn_sT, T, E, I);
    hipLaunchKernelGGL(k_spkconv, dim3(NB + NCONV), dim3(64), 0, stream,
                       syn_sT, Theta_s, spike_decay, C_den, W_s_prop,
                       Zout, Xout, Z_T, PZ_T,
                       in_eT, in_iT, ke, ki, syn_nsT, T, NB);
    hipLaunchKernelGGL(k_A, dim3((SUB * T4 + 255) / 256), dim3(256), 0, stream,
                       syn_nsT, PZ_T, Z_T, histk, propk, Theta_ns, A_T, T);
    hipLaunchKernelGGL(k_y, dim3(NB), dim3(64), 0, stream,
                       A_T, C_den, W_ns_sub, V_o, Vout, Yout, T);
}